// Round 1
// baseline (225.969 us; speedup 1.0000x reference)
//
#include <hip/hip_runtime.h>
#include <hip/hip_bf16.h>
#include <cstddef>

#define T_LEN 32
#define E_LEN 256
#define BATCH 16
#define DIM 512
#define HID 512
#define WROW 1024  // HID + DIM

// ---------------------------------------------------------------------------
// GEMM (NT): C[m,n] = sum_k A[m*512+k] * W[n*ldw + k]  (+ bias[n] if bias)
// M % 64 == 0, N = 512, K = 512 fixed.
// ---------------------------------------------------------------------------
__global__ __launch_bounds__(256) void gemm_nt(const float* __restrict__ A,
                                               const float* __restrict__ W, int ldw,
                                               const float* __restrict__ bias,
                                               float* __restrict__ C, int M) {
    const int BM = 64, BN = 64, BK = 16;
    __shared__ float As[BK][BM];
    __shared__ float Bs[BK][BN];
    const int tid = threadIdx.x;
    const int m0 = blockIdx.y * BM;
    const int n0 = blockIdx.x * BN;
    const int tx = tid & 15;        // 0..15 -> 4 cols each
    const int ty = tid >> 4;        // 0..15 -> 4 rows each
    const int lr = tid >> 2;        // 0..63 row of tile for load
    const int lc = (tid & 3) * 4;   // 0,4,8,12 k-col of tile for load

    float acc[4][4] = {};

    for (int k0 = 0; k0 < 512; k0 += BK) {
        float4 av = *(const float4*)(A + (size_t)(m0 + lr) * 512 + k0 + lc);
        float4 wv = *(const float4*)(W + (size_t)(n0 + lr) * ldw + k0 + lc);
        __syncthreads();
        As[lc + 0][lr] = av.x; As[lc + 1][lr] = av.y;
        As[lc + 2][lr] = av.z; As[lc + 3][lr] = av.w;
        Bs[lc + 0][lr] = wv.x; Bs[lc + 1][lr] = wv.y;
        Bs[lc + 2][lr] = wv.z; Bs[lc + 3][lr] = wv.w;
        __syncthreads();
#pragma unroll
        for (int k = 0; k < BK; ++k) {
            float4 a = *(const float4*)&As[k][ty * 4];
            float4 b = *(const float4*)&Bs[k][tx * 4];
            float ar[4] = {a.x, a.y, a.z, a.w};
            float br[4] = {b.x, b.y, b.z, b.w};
#pragma unroll
            for (int i = 0; i < 4; ++i)
#pragma unroll
                for (int j = 0; j < 4; ++j) acc[i][j] += ar[i] * br[j];
        }
    }
#pragma unroll
    for (int i = 0; i < 4; ++i) {
        int m = m0 + ty * 4 + i;
#pragma unroll
        for (int j = 0; j < 4; ++j) {
            int n = n0 + tx * 4 + j;
            float v = acc[i][j];
            if (bias) v += bias[n];
            C[(size_t)m * 512 + n] = v;
        }
    }
}

// ---------------------------------------------------------------------------
// Energies: EN[b,t,e] = v . tanh(PT[t*B+b,:] + PE[e*B+b,:]) + b_score, masked.
// One block per (b,t); one wave per e (4 e's concurrently).
// PT already contains +b_attn.
// ---------------------------------------------------------------------------
__global__ __launch_bounds__(256) void energies_k(const float* __restrict__ PT,
                                                  const float* __restrict__ PE,
                                                  const float* __restrict__ v,
                                                  const float* __restrict__ bscore,
                                                  const int* __restrict__ mask,
                                                  float* __restrict__ EN) {
    const int b = blockIdx.x / T_LEN;
    const int t = blockIdx.x % T_LEN;
    __shared__ float spt[HID];
    __shared__ float sv[HID];
    const int tid = threadIdx.x;
    const int ptRow = t * BATCH + b;
    for (int i = tid; i < HID; i += 256) {
        spt[i] = PT[(size_t)ptRow * HID + i];
        sv[i] = v[i];
    }
    __syncthreads();
    const int lane = tid & 63;
    const int wid = tid >> 6;
    const float bs = bscore[0];
    for (int e = wid; e < E_LEN; e += 4) {
        const float* pe = PE + (size_t)(e * BATCH + b) * HID;
        float acc = 0.f;
#pragma unroll
        for (int j = 0; j < 8; ++j) {
            int h = lane + 64 * j;
            float x = spt[h] + pe[h];
            float ex = __expf(2.f * x);
            float th = 1.f - 2.f / (ex + 1.f);
            acc = fmaf(sv[h], th, acc);
        }
#pragma unroll
        for (int off = 32; off; off >>= 1) acc += __shfl_down(acc, off);
        if (lane == 0) {
            float en = acc + bs;
            if (mask[e * BATCH + b] != 0) en = -1e12f;
            EN[((size_t)b * T_LEN + t) * E_LEN + e] = en;
        }
    }
}

// ---------------------------------------------------------------------------
// new_exp[b,e,d] = sum_t softmax_t(EN[b,:,e])[t] * topic[t,b,d]
// One wave (64 threads) per (b,e).
// ---------------------------------------------------------------------------
__global__ __launch_bounds__(64) void new_exp_k(const float* __restrict__ EN,
                                                const float* __restrict__ topic,
                                                float* __restrict__ out) {
    const int b = blockIdx.x / E_LEN;
    const int e = blockIdx.x % E_LEN;
    const int lane = threadIdx.x;
    __shared__ float w[T_LEN];
    float x = (lane < T_LEN) ? EN[((size_t)b * T_LEN + lane) * E_LEN + e] : -3e38f;
    float m = x;
#pragma unroll
    for (int off = 32; off; off >>= 1) m = fmaxf(m, __shfl_xor(m, off));
    float p = (lane < T_LEN) ? __expf(x - m) : 0.f;
    float s = p;
#pragma unroll
    for (int off = 32; off; off >>= 1) s += __shfl_xor(s, off);
    if (lane < T_LEN) w[lane] = p / s;
    __syncthreads();
    float acc[8] = {};
    for (int t = 0; t < T_LEN; ++t) {
        const float wt = w[t];
        const float* row = topic + ((size_t)t * BATCH + b) * DIM;
#pragma unroll
        for (int j = 0; j < 8; ++j) acc[j] = fmaf(wt, row[lane + 64 * j], acc[j]);
    }
    float* o = out + ((size_t)b * E_LEN + e) * DIM;
#pragma unroll
    for (int j = 0; j < 8; ++j) o[lane + 64 * j] = acc[j];
}

// ---------------------------------------------------------------------------
// new_topic[b,t,d] = sum_e softmax_e(EN[b,t,:])[e] * exp_output[e,b,d]
// One block (256 threads) per (b,t).
// ---------------------------------------------------------------------------
__global__ __launch_bounds__(256) void new_topic_k(const float* __restrict__ EN,
                                                   const float* __restrict__ expo,
                                                   float* __restrict__ out) {
    const int b = blockIdx.x / T_LEN;
    const int t = blockIdx.x % T_LEN;
    const int tid = threadIdx.x;
    __shared__ float w[E_LEN];
    __shared__ float wred[4];
    float x = EN[((size_t)b * T_LEN + t) * E_LEN + tid];
    const int lane = tid & 63;
    const int wid = tid >> 6;
    float m = x;
#pragma unroll
    for (int off = 32; off; off >>= 1) m = fmaxf(m, __shfl_xor(m, off));
    if (lane == 0) wred[wid] = m;
    __syncthreads();
    m = fmaxf(fmaxf(wred[0], wred[1]), fmaxf(wred[2], wred[3]));
    float p = __expf(x - m);
    float s = p;
#pragma unroll
    for (int off = 32; off; off >>= 1) s += __shfl_xor(s, off);
    __syncthreads();
    if (lane == 0) wred[wid] = s;
    __syncthreads();
    s = wred[0] + wred[1] + wred[2] + wred[3];
    w[tid] = p / s;
    __syncthreads();
    float acc0 = 0.f, acc1 = 0.f;
    for (int e = 0; e < E_LEN; ++e) {
        const float* row = expo + ((size_t)e * BATCH + b) * DIM;
        const float we = w[e];
        acc0 = fmaf(we, row[tid], acc0);
        acc1 = fmaf(we, row[tid + 256], acc1);
    }
    float* o = out + ((size_t)b * T_LEN + t) * DIM;
    o[tid] = acc0;
    o[tid + 256] = acc1;
}

extern "C" void kernel_launch(void* const* d_in, const int* in_sizes, int n_in,
                              void* d_out, int out_size, void* d_ws, size_t ws_size,
                              hipStream_t stream) {
    const float* topic = (const float*)d_in[0];   // [T,B,D]
    const float* expo  = (const float*)d_in[1];   // [E,B,D]
    const int*   mask  = (const int*)d_in[2];     // [E,B] (bool as int32)
    const float* W     = (const float*)d_in[3];   // [H, H+D]
    const float* battn = (const float*)d_in[4];   // [H]
    const float* vsc   = (const float*)d_in[5];   // [1,H]
    const float* bsc   = (const float*)d_in[6];   // [1]
    float* out = (float*)d_out;                   // new_topic [B,T,D] ++ new_exp [B,E,D]

    float* PT = (float*)d_ws;                     // [T*B, H]   262144 floats
    float* PE = PT + (size_t)T_LEN * BATCH * HID; // [E*B, H]   2097152 floats
    float* EN = PE + (size_t)E_LEN * BATCH * HID; // [B,T,E]    131072 floats

    // proj_t = topic @ W[:, :D]^T + b_attn   (M = T*B = 512)
    gemm_nt<<<dim3(8, (T_LEN * BATCH) / 64), 256, 0, stream>>>(topic, W, WROW, battn, PT,
                                                               T_LEN * BATCH);
    // proj_e = exp @ W[:, D:]^T              (M = E*B = 4096)
    gemm_nt<<<dim3(8, (E_LEN * BATCH) / 64), 256, 0, stream>>>(expo, W + DIM, WROW, nullptr, PE,
                                                               E_LEN * BATCH);
    energies_k<<<BATCH * T_LEN, 256, 0, stream>>>(PT, PE, vsc, bsc, mask, EN);
    new_exp_k<<<BATCH * E_LEN, 64, 0, stream>>>(EN, topic, out + (size_t)BATCH * T_LEN * DIM);
    new_topic_k<<<BATCH * T_LEN, 256, 0, stream>>>(EN, expo, out);
}

// Round 2
// 159.967 us; speedup vs baseline: 1.4126x; 1.4126x over previous
//
#include <hip/hip_runtime.h>
#include <hip/hip_bf16.h>
#include <cstddef>
#include <cstdint>

#define T_LEN 32
#define E_LEN 256
#define BATCH 16
#define DIM 512
#define HID 512
#define WROW 1024  // HID + DIM

typedef __attribute__((ext_vector_type(8))) short bf16x8;
typedef __attribute__((ext_vector_type(4))) float f32x4;

// ---------------------------------------------------------------------------
// f32 -> bf16 cast (RNE), n multiple of 8
// ---------------------------------------------------------------------------
__global__ void cast_bf16_k(const float* __restrict__ src,
                            __hip_bfloat16* __restrict__ dst, int n) {
    int i = (blockIdx.x * blockDim.x + threadIdx.x) * 8;
    if (i >= n) return;
    float4 a = *(const float4*)(src + i);
    float4 b = *(const float4*)(src + i + 4);
    union { bf16x8 v; __hip_bfloat16 h[8]; } u;
    u.h[0] = __float2bfloat16(a.x); u.h[1] = __float2bfloat16(a.y);
    u.h[2] = __float2bfloat16(a.z); u.h[3] = __float2bfloat16(a.w);
    u.h[4] = __float2bfloat16(b.x); u.h[5] = __float2bfloat16(b.y);
    u.h[6] = __float2bfloat16(b.z); u.h[7] = __float2bfloat16(b.w);
    *(bf16x8*)(dst + i) = u.v;
}

// ---------------------------------------------------------------------------
// bf16 MFMA GEMM (NT): C[m,n] = sum_k A[m,k] * W[n,k]  (+bias[n])
// A: [M][512] bf16 row-major.  W: [512][ldw] bf16, use given pointer (column
// offset pre-applied).  C: [M][512] f32.  Tile 64x64, BK=64, 256 threads.
// Wave w owns m-rows w*16..w*16+15; 4 n-tiles of 16.
// mfma_f32_16x16x32_bf16: A-frag A[m=lane&15][k=(lane>>4)*8+j];
// C/D: col=lane&15, row=(lane>>4)*4+reg   (m89-verified).
// ---------------------------------------------------------------------------
#define GPAD 8
#define GLDR (64 + GPAD)  // halfword row stride (144 B: 16B aligned rows)

__global__ __launch_bounds__(256) void gemm_bf16_nt(
    const __hip_bfloat16* __restrict__ A, const __hip_bfloat16* __restrict__ W,
    int ldw, const float* __restrict__ bias, float* __restrict__ C, int M) {
    __shared__ __hip_bfloat16 As[64 * GLDR];
    __shared__ __hip_bfloat16 Bs[64 * GLDR];
    const int tid = threadIdx.x;
    const int m0 = blockIdx.y * 64;
    const int n0 = blockIdx.x * 64;
    const int w = tid >> 6;
    const int lane = tid & 63;
    const int l15 = lane & 15;
    const int g = lane >> 4;

    const int srow = tid >> 2;   // staging row 0..63
    const int sc = tid & 3;      // staging chunks sc, sc+4 (8 bf16 each)

    f32x4 acc[4];
    const f32x4 z = {0.f, 0.f, 0.f, 0.f};
#pragma unroll
    for (int nt = 0; nt < 4; ++nt) acc[nt] = z;

    const __hip_bfloat16* ga = A + (size_t)(m0 + srow) * 512 + sc * 8;
    const __hip_bfloat16* gb = W + (size_t)(n0 + srow) * ldw + sc * 8;

    for (int kk = 0; kk < 8; ++kk) {
        bf16x8 a0 = *(const bf16x8*)(ga);
        bf16x8 a1 = *(const bf16x8*)(ga + 32);
        bf16x8 b0 = *(const bf16x8*)(gb);
        bf16x8 b1 = *(const bf16x8*)(gb + 32);
        ga += 64; gb += 64;
        __syncthreads();
        *(bf16x8*)&As[srow * GLDR + sc * 8] = a0;
        *(bf16x8*)&As[srow * GLDR + (sc + 4) * 8] = a1;
        *(bf16x8*)&Bs[srow * GLDR + sc * 8] = b0;
        *(bf16x8*)&Bs[srow * GLDR + (sc + 4) * 8] = b1;
        __syncthreads();
#pragma unroll
        for (int s = 0; s < 2; ++s) {
            bf16x8 af = *(const bf16x8*)&As[(w * 16 + l15) * GLDR + (s * 4 + g) * 8];
#pragma unroll
            for (int nt = 0; nt < 4; ++nt) {
                bf16x8 bf = *(const bf16x8*)&Bs[(nt * 16 + l15) * GLDR + (s * 4 + g) * 8];
                acc[nt] = __builtin_amdgcn_mfma_f32_16x16x32_bf16(af, bf, acc[nt], 0, 0, 0);
            }
        }
    }
#pragma unroll
    for (int nt = 0; nt < 4; ++nt) {
        int n = n0 + nt * 16 + l15;
        float bv = bias ? bias[n] : 0.f;
#pragma unroll
        for (int r = 0; r < 4; ++r) {
            int m = m0 + w * 16 + g * 4 + r;
            C[(size_t)m * 512 + n] = acc[nt][r] + bv;
        }
    }
}

// ---------------------------------------------------------------------------
// Energies. Block = (b, t-group of 4, e-chunk of 32); wave handles 8 e's.
// All operands register-resident; PE read once per 4 t's.
// EN[b,t,e] = v . tanh(PT[t*B+b,:] + PE[e*B+b,:]) + b_score, masked -1e12.
// ---------------------------------------------------------------------------
__global__ __launch_bounds__(256) void energies_k(const float* __restrict__ PT,
                                                  const float* __restrict__ PE,
                                                  const float* __restrict__ v,
                                                  const float* __restrict__ bscore,
                                                  const int* __restrict__ mask,
                                                  float* __restrict__ EN) {
    const int b = blockIdx.x;
    const int tg = blockIdx.y;   // t = tg*4 + i
    const int ech = blockIdx.z;  // e base = ech*32
    const int lane = threadIdx.x & 63;
    const int w = threadIdx.x >> 6;
    const int h0 = lane * 8;

    float sv[8], spt[4][8];
    {
        float4 v0 = *(const float4*)(v + h0);
        float4 v1 = *(const float4*)(v + h0 + 4);
        sv[0] = v0.x; sv[1] = v0.y; sv[2] = v0.z; sv[3] = v0.w;
        sv[4] = v1.x; sv[5] = v1.y; sv[6] = v1.z; sv[7] = v1.w;
#pragma unroll
        for (int i = 0; i < 4; ++i) {
            const float* p = PT + ((size_t)((tg * 4 + i) * BATCH + b)) * HID + h0;
            float4 p0 = *(const float4*)(p);
            float4 p1 = *(const float4*)(p + 4);
            spt[i][0] = p0.x; spt[i][1] = p0.y; spt[i][2] = p0.z; spt[i][3] = p0.w;
            spt[i][4] = p1.x; spt[i][5] = p1.y; spt[i][6] = p1.z; spt[i][7] = p1.w;
        }
    }
    const int e0 = ech * 32 + w * 8;
    for (int ei = 0; ei < 8; ++ei) {
        const int e = e0 + ei;
        const float* pe = PE + ((size_t)(e * BATCH + b)) * HID + h0;
        float4 p0 = *(const float4*)(pe);
        float4 p1 = *(const float4*)(pe + 4);
        float pr[8] = {p0.x, p0.y, p0.z, p0.w, p1.x, p1.y, p1.z, p1.w};
        float acc[4] = {0.f, 0.f, 0.f, 0.f};
#pragma unroll
        for (int i = 0; i < 4; ++i) {
#pragma unroll
            for (int j = 0; j < 8; ++j) {
                float x = spt[i][j] + pr[j];
                float ex = __expf(2.f * x);
                float th = 1.f - __fdividef(2.f, ex + 1.f);
                acc[i] = fmaf(sv[j], th, acc[i]);
            }
        }
#pragma unroll
        for (int i = 0; i < 4; ++i) {
#pragma unroll
            for (int off = 32; off; off >>= 1) acc[i] += __shfl_xor(acc[i], off);
        }
        if (lane == 0) {
            const float bs = bscore[0];
            const int msk = mask[e * BATCH + b];
#pragma unroll
            for (int i = 0; i < 4; ++i) {
                float en = acc[i] + bs;
                if (msk != 0) en = -1e12f;
                EN[((size_t)b * T_LEN + tg * 4 + i) * E_LEN + e] = en;
            }
        }
    }
}

// ---------------------------------------------------------------------------
// new_exp[b,e,d] = sum_t softmax_t(EN[b,:,e])[t] * topic[t,b,d]
// 256 threads = 4 waves; one wave per (b,e). Shuffle-only softmax.
// ---------------------------------------------------------------------------
__global__ __launch_bounds__(256) void new_exp_k(const float* __restrict__ EN,
                                                 const float* __restrict__ topic,
                                                 float* __restrict__ out) {
    const int idx = blockIdx.x * 4 + (threadIdx.x >> 6);  // b*E_LEN + e
    const int b = idx >> 8;
    const int e = idx & 255;
    const int lane = threadIdx.x & 63;
    float x = (lane < T_LEN) ? EN[((size_t)b * T_LEN + lane) * E_LEN + e] : -3e38f;
    float m = x;
#pragma unroll
    for (int off = 16; off; off >>= 1) m = fmaxf(m, __shfl_xor(m, off));
    float p = (lane < T_LEN) ? __expf(x - m) : 0.f;
    float s = p;
#pragma unroll
    for (int off = 16; off; off >>= 1) s += __shfl_xor(s, off);
    float wv = __fdividef(p, s);
    float acc[8] = {};
    for (int t = 0; t < T_LEN; ++t) {
        const float wt = __shfl(wv, t);
        const float* row = topic + ((size_t)t * BATCH + b) * DIM;
#pragma unroll
        for (int j = 0; j < 8; ++j) acc[j] = fmaf(wt, row[lane + 64 * j], acc[j]);
    }
    float* o = out + ((size_t)b * E_LEN + e) * DIM;
#pragma unroll
    for (int j = 0; j < 8; ++j) o[lane + 64 * j] = acc[j];
}

// ---------------------------------------------------------------------------
// new_topic[b,t,d] = sum_e softmax_e(EN[b,t,:])[e] * exp_output[e,b,d]
// One block (256 threads) per (b,t).
// ---------------------------------------------------------------------------
__global__ __launch_bounds__(256) void new_topic_k(const float* __restrict__ EN,
                                                   const float* __restrict__ expo,
                                                   float* __restrict__ out) {
    const int b = blockIdx.x / T_LEN;
    const int t = blockIdx.x % T_LEN;
    const int tid = threadIdx.x;
    __shared__ float wsm[E_LEN];
    __shared__ float wred[4];
    float x = EN[((size_t)b * T_LEN + t) * E_LEN + tid];
    const int lane = tid & 63;
    const int wid = tid >> 6;
    float m = x;
#pragma unroll
    for (int off = 32; off; off >>= 1) m = fmaxf(m, __shfl_xor(m, off));
    if (lane == 0) wred[wid] = m;
    __syncthreads();
    m = fmaxf(fmaxf(wred[0], wred[1]), fmaxf(wred[2], wred[3]));
    float p = __expf(x - m);
    float s = p;
#pragma unroll
    for (int off = 32; off; off >>= 1) s += __shfl_xor(s, off);
    __syncthreads();
    if (lane == 0) wred[wid] = s;
    __syncthreads();
    s = wred[0] + wred[1] + wred[2] + wred[3];
    wsm[tid] = __fdividef(p, s);
    __syncthreads();
    float acc0 = 0.f, acc1 = 0.f;
    for (int e = 0; e < E_LEN; ++e) {
        const float* row = expo + ((size_t)e * BATCH + b) * DIM;
        const float we = wsm[e];
        acc0 = fmaf(we, row[tid], acc0);
        acc1 = fmaf(we, row[tid + 256], acc1);
    }
    float* o = out + ((size_t)b * T_LEN + t) * DIM;
    o[tid] = acc0;
    o[tid + 256] = acc1;
}

extern "C" void kernel_launch(void* const* d_in, const int* in_sizes, int n_in,
                              void* d_out, int out_size, void* d_ws, size_t ws_size,
                              hipStream_t stream) {
    const float* topic = (const float*)d_in[0];   // [T,B,D]
    const float* expo  = (const float*)d_in[1];   // [E,B,D]
    const int*   mask  = (const int*)d_in[2];     // [E,B]
    const float* W     = (const float*)d_in[3];   // [H, H+D]
    const float* battn = (const float*)d_in[4];   // [H]
    const float* vsc   = (const float*)d_in[5];   // [1,H]
    const float* bsc   = (const float*)d_in[6];   // [1]
    float* out = (float*)d_out;                   // new_topic [B,T,D] ++ new_exp [B,E,D]

    const size_t nTop = (size_t)T_LEN * BATCH * DIM;   // 262144
    const size_t nExp = (size_t)E_LEN * BATCH * DIM;   // 2097152
    const size_t nW   = (size_t)HID * WROW;            // 524288

    float* PT = (float*)d_ws;                          // 1 MB
    float* PE = PT + (size_t)T_LEN * BATCH * HID;      // 8 MB
    float* EN = PE + (size_t)E_LEN * BATCH * HID;      // 0.5 MB
    __hip_bfloat16* topicB = (__hip_bfloat16*)(EN + (size_t)BATCH * T_LEN * E_LEN);
    __hip_bfloat16* expoB  = topicB + nTop;
    __hip_bfloat16* WB     = expoB + nExp;

    cast_bf16_k<<<(int)(nTop / 8 / 256), 256, 0, stream>>>(topic, topicB, (int)nTop);
    cast_bf16_k<<<(int)(nExp / 8 / 256), 256, 0, stream>>>(expo, expoB, (int)nExp);
    cast_bf16_k<<<(int)(nW / 8 / 256), 256, 0, stream>>>(W, WB, (int)nW);

    // proj_t = topic @ W[:, :D]^T + b_attn   (M = 512)
    gemm_bf16_nt<<<dim3(8, 8), 256, 0, stream>>>(topicB, WB, WROW, battn, PT, 512);
    // proj_e = exp @ W[:, D:]^T              (M = 4096)
    gemm_bf16_nt<<<dim3(8, 64), 256, 0, stream>>>(expoB, WB + DIM, WROW, nullptr, PE, 4096);

    energies_k<<<dim3(BATCH, 8, 8), 256, 0, stream>>>(PT, PE, vsc, bsc, mask, EN);
    new_exp_k<<<BATCH * E_LEN / 4, 256, 0, stream>>>(EN, topic, out + (size_t)BATCH * T_LEN * DIM);
    new_topic_k<<<BATCH * T_LEN, 256, 0, stream>>>(EN, expo, out);
}

// Round 3
// 133.019 us; speedup vs baseline: 1.6988x; 1.2026x over previous
//
#include <hip/hip_runtime.h>
#include <hip/hip_bf16.h>
#include <cstddef>
#include <cstdint>

#define T_LEN 32
#define E_LEN 256
#define BATCH 16
#define DIM 512
#define HID 512
#define WROW 1024  // HID + DIM

#define TWO_LOG2E 2.8853900817779268f  // 2*log2(e)

typedef __attribute__((ext_vector_type(8))) short bf16x8;
typedef __attribute__((ext_vector_type(4))) float f32x4;

__device__ inline bf16x8 cvt8(float4 a, float4 b) {
    union { bf16x8 v; __hip_bfloat16 h[8]; } u;
    u.h[0] = __float2bfloat16(a.x); u.h[1] = __float2bfloat16(a.y);
    u.h[2] = __float2bfloat16(a.z); u.h[3] = __float2bfloat16(a.w);
    u.h[4] = __float2bfloat16(b.x); u.h[5] = __float2bfloat16(b.y);
    u.h[6] = __float2bfloat16(b.z); u.h[7] = __float2bfloat16(b.w);
    return u.v;
}

// ---------------------------------------------------------------------------
// Fused projection GEMM (NT), f32 in -> bf16 MFMA -> f32 out, pre-scaled.
// blockIdx.y < 8: PT' = TWO_LOG2E*(topic @ W[:, :D]^T + b_attn)   (M=512)
// blockIdx.y >= 8: PE' = TWO_LOG2E*(expo @ W[:, D:]^T)            (M=4096)
// Tile 64x64, BK=64, 256 threads. mfma_f32_16x16x32_bf16 (m89 layouts).
// ---------------------------------------------------------------------------
#define GPAD 8
#define GLDR (64 + GPAD)

__global__ __launch_bounds__(256) void gemm_fused(
    const float* __restrict__ topic, const float* __restrict__ expo,
    const float* __restrict__ W, const float* __restrict__ battn,
    float* __restrict__ PT, float* __restrict__ PE) {
    __shared__ __hip_bfloat16 As[64 * GLDR];
    __shared__ __hip_bfloat16 Bs[64 * GLDR];
    const int tid = threadIdx.x;
    const int by = blockIdx.y;
    const float* A; const float* Wp; const float* bias; float* C; int m0;
    if (by < 8) { A = topic; Wp = W;       bias = battn;   C = PT; m0 = by * 64; }
    else        { A = expo;  Wp = W + DIM; bias = nullptr; C = PE; m0 = (by - 8) * 64; }
    const int n0 = blockIdx.x * 64;
    const int w = tid >> 6;
    const int lane = tid & 63;
    const int l15 = lane & 15;
    const int g = lane >> 4;
    const int srow = tid >> 2;   // 0..63
    const int sc = tid & 3;      // halfword chunks at sc*8 and sc*8+32

    f32x4 acc[4];
    const f32x4 z = {0.f, 0.f, 0.f, 0.f};
#pragma unroll
    for (int nt = 0; nt < 4; ++nt) acc[nt] = z;

    const float* ga = A + (size_t)(m0 + srow) * 512 + sc * 8;
    const float* gb = Wp + (size_t)(n0 + srow) * WROW + sc * 8;

    for (int kk = 0; kk < 8; ++kk) {
        float4 a0 = *(const float4*)(ga);
        float4 a1 = *(const float4*)(ga + 4);
        float4 a2 = *(const float4*)(ga + 32);
        float4 a3 = *(const float4*)(ga + 36);
        float4 b0 = *(const float4*)(gb);
        float4 b1 = *(const float4*)(gb + 4);
        float4 b2 = *(const float4*)(gb + 32);
        float4 b3 = *(const float4*)(gb + 36);
        ga += 64; gb += 64;
        bf16x8 av0 = cvt8(a0, a1), av1 = cvt8(a2, a3);
        bf16x8 bv0 = cvt8(b0, b1), bv1 = cvt8(b2, b3);
        __syncthreads();
        *(bf16x8*)&As[srow * GLDR + sc * 8] = av0;
        *(bf16x8*)&As[srow * GLDR + sc * 8 + 32] = av1;
        *(bf16x8*)&Bs[srow * GLDR + sc * 8] = bv0;
        *(bf16x8*)&Bs[srow * GLDR + sc * 8 + 32] = bv1;
        __syncthreads();
#pragma unroll
        for (int s = 0; s < 2; ++s) {
            bf16x8 af = *(const bf16x8*)&As[(w * 16 + l15) * GLDR + (s * 4 + g) * 8];
#pragma unroll
            for (int nt = 0; nt < 4; ++nt) {
                bf16x8 bf = *(const bf16x8*)&Bs[(nt * 16 + l15) * GLDR + (s * 4 + g) * 8];
                acc[nt] = __builtin_amdgcn_mfma_f32_16x16x32_bf16(af, bf, acc[nt], 0, 0, 0);
            }
        }
    }
#pragma unroll
    for (int nt = 0; nt < 4; ++nt) {
        int n = n0 + nt * 16 + l15;
        float bv = bias ? bias[n] : 0.f;
#pragma unroll
        for (int r = 0; r < 4; ++r) {
            int m = m0 + w * 16 + g * 4 + r;
            C[(size_t)m * 512 + n] = (acc[nt][r] + bv) * TWO_LOG2E;
        }
    }
}

// ---------------------------------------------------------------------------
// Energies. PT'/PE' carry the 2*log2e scale, so per element:
// x = pt'+pe'; r = rcp(exp2(x)+1); acc += (-2 v)*r; en = sum(v)+bs+acc.
// Block = (b, 4 t's, 16 e's); wave handles 4 e's x 4 t's. Grid 2048 blocks.
// ---------------------------------------------------------------------------
__global__ __launch_bounds__(256) void energies_k(const float* __restrict__ PT,
                                                  const float* __restrict__ PE,
                                                  const float* __restrict__ v,
                                                  const float* __restrict__ bscore,
                                                  const int* __restrict__ mask,
                                                  float* __restrict__ EN) {
    const int b = blockIdx.x;
    const int tg = blockIdx.y;   // t = tg*4 + i
    const int ech = blockIdx.z;  // e base = ech*16
    const int lane = threadIdx.x & 63;
    const int w = threadIdx.x >> 6;
    const int h0 = lane * 8;

    float sv[8], spt[4][8];
    float sumv;
    {
        float4 v0 = *(const float4*)(v + h0);
        float4 v1 = *(const float4*)(v + h0 + 4);
        float vr[8] = {v0.x, v0.y, v0.z, v0.w, v1.x, v1.y, v1.z, v1.w};
        float s = 0.f;
#pragma unroll
        for (int j = 0; j < 8; ++j) { sv[j] = -2.f * vr[j]; s += vr[j]; }
#pragma unroll
        for (int off = 32; off; off >>= 1) s += __shfl_xor(s, off);
        sumv = s;
#pragma unroll
        for (int i = 0; i < 4; ++i) {
            const float* p = PT + ((size_t)((tg * 4 + i) * BATCH + b)) * HID + h0;
            float4 p0 = *(const float4*)(p);
            float4 p1 = *(const float4*)(p + 4);
            spt[i][0] = p0.x; spt[i][1] = p0.y; spt[i][2] = p0.z; spt[i][3] = p0.w;
            spt[i][4] = p1.x; spt[i][5] = p1.y; spt[i][6] = p1.z; spt[i][7] = p1.w;
        }
    }
    const int e0 = ech * 16 + w * 4;
    const float bs = bscore[0];
#pragma unroll
    for (int ei = 0; ei < 4; ++ei) {
        const int e = e0 + ei;
        const float* pe = PE + ((size_t)(e * BATCH + b)) * HID + h0;
        float4 p0 = *(const float4*)(pe);
        float4 p1 = *(const float4*)(pe + 4);
        float pr[8] = {p0.x, p0.y, p0.z, p0.w, p1.x, p1.y, p1.z, p1.w};
        float acc[4] = {0.f, 0.f, 0.f, 0.f};
#pragma unroll
        for (int i = 0; i < 4; ++i) {
#pragma unroll
            for (int j = 0; j < 8; ++j) {
                float x = spt[i][j] + pr[j];
                float ex = __builtin_amdgcn_exp2f(x);
                float r = __builtin_amdgcn_rcpf(ex + 1.f);
                acc[i] = fmaf(sv[j], r, acc[i]);
            }
        }
#pragma unroll
        for (int i = 0; i < 4; ++i) {
#pragma unroll
            for (int off = 32; off; off >>= 1) acc[i] += __shfl_xor(acc[i], off);
        }
        if (lane == 0) {
            const int msk = mask[e * BATCH + b];
#pragma unroll
            for (int i = 0; i < 4; ++i) {
                float en = sumv + bs + acc[i];
                if (msk != 0) en = -1e12f;
                EN[((size_t)b * T_LEN + tg * 4 + i) * E_LEN + e] = en;
            }
        }
    }
}

// ---------------------------------------------------------------------------
// new_exp[b,e,d] = sum_t softmax_t(EN[b,:,e])[t] * topic[t,b,d]
// 4 waves/block; one wave per (b,e). Shuffle-only softmax.
// ---------------------------------------------------------------------------
__global__ __launch_bounds__(256) void new_exp_k(const float* __restrict__ EN,
                                                 const float* __restrict__ topic,
                                                 float* __restrict__ out) {
    const int idx = blockIdx.x * 4 + (threadIdx.x >> 6);  // b*E_LEN + e
    const int b = idx >> 8;
    const int e = idx & 255;
    const int lane = threadIdx.x & 63;
    float x = (lane < T_LEN) ? EN[((size_t)b * T_LEN + lane) * E_LEN + e] : -3e38f;
    float m = x;
#pragma unroll
    for (int off = 16; off; off >>= 1) m = fmaxf(m, __shfl_xor(m, off));
    float p = (lane < T_LEN) ? __expf(x - m) : 0.f;
    float s = p;
#pragma unroll
    for (int off = 16; off; off >>= 1) s += __shfl_xor(s, off);
    float wv = __fdividef(p, s);
    float acc[8] = {};
    for (int t = 0; t < T_LEN; ++t) {
        const float wt = __shfl(wv, t);
        const float* row = topic + ((size_t)t * BATCH + b) * DIM;
#pragma unroll
        for (int j = 0; j < 8; ++j) acc[j] = fmaf(wt, row[lane + 64 * j], acc[j]);
    }
    float* o = out + ((size_t)b * E_LEN + e) * DIM;
#pragma unroll
    for (int j = 0; j < 8; ++j) o[lane + 64 * j] = acc[j];
}

// ---------------------------------------------------------------------------
// new_topic[b,t,d] = sum_e softmax_e(EN[b,t,:])[e] * exp_output[e,b,d]
// One block (256 threads) per (b,t); float2 per thread, unroll-8 e-loop.
// ---------------------------------------------------------------------------
__global__ __launch_bounds__(256) void new_topic_k(const float* __restrict__ EN,
                                                   const float* __restrict__ expo,
                                                   float* __restrict__ out) {
    const int b = blockIdx.x / T_LEN;
    const int t = blockIdx.x % T_LEN;
    const int tid = threadIdx.x;
    __shared__ float wsm[E_LEN];
    __shared__ float wred[4];
    float x = EN[((size_t)b * T_LEN + t) * E_LEN + tid];
    const int lane = tid & 63;
    const int wid = tid >> 6;
    float m = x;
#pragma unroll
    for (int off = 32; off; off >>= 1) m = fmaxf(m, __shfl_xor(m, off));
    if (lane == 0) wred[wid] = m;
    __syncthreads();
    m = fmaxf(fmaxf(wred[0], wred[1]), fmaxf(wred[2], wred[3]));
    float p = __expf(x - m);
    float s = p;
#pragma unroll
    for (int off = 32; off; off >>= 1) s += __shfl_xor(s, off);
    __syncthreads();
    if (lane == 0) wred[wid] = s;
    __syncthreads();
    s = wred[0] + wred[1] + wred[2] + wred[3];
    wsm[tid] = __fdividef(p, s);
    __syncthreads();
    const float2* ex2 = (const float2*)expo;  // row stride 256 float2
    float2 acc = {0.f, 0.f};
#pragma unroll 8
    for (int e = 0; e < E_LEN; ++e) {
        float2 rv = ex2[(size_t)(e * BATCH + b) * 256 + tid];
        const float we = wsm[e];
        acc.x = fmaf(we, rv.x, acc.x);
        acc.y = fmaf(we, rv.y, acc.y);
    }
    float2* o = (float2*)(out + ((size_t)b * T_LEN + t) * DIM);
    o[tid] = acc;
}

extern "C" void kernel_launch(void* const* d_in, const int* in_sizes, int n_in,
                              void* d_out, int out_size, void* d_ws, size_t ws_size,
                              hipStream_t stream) {
    const float* topic = (const float*)d_in[0];   // [T,B,D]
    const float* expo  = (const float*)d_in[1];   // [E,B,D]
    const int*   mask  = (const int*)d_in[2];     // [E,B]
    const float* W     = (const float*)d_in[3];   // [H, H+D]
    const float* battn = (const float*)d_in[4];   // [H]
    const float* vsc   = (const float*)d_in[5];   // [1,H]
    const float* bsc   = (const float*)d_in[6];   // [1]
    float* out = (float*)d_out;                   // new_topic [B,T,D] ++ new_exp [B,E,D]

    float* PT = (float*)d_ws;                     // [512, 512]  1 MB
    float* PE = PT + (size_t)T_LEN * BATCH * HID; // [4096, 512] 8 MB
    float* EN = PE + (size_t)E_LEN * BATCH * HID; // [B,T,E]     0.5 MB

    gemm_fused<<<dim3(8, 72), 256, 0, stream>>>(topic, expo, W, battn, PT, PE);
    energies_k<<<dim3(BATCH, 8, 16), 256, 0, stream>>>(PT, PE, vsc, bsc, mask, EN);
    new_exp_k<<<BATCH * E_LEN / 4, 256, 0, stream>>>(EN, topic, out + (size_t)BATCH * T_LEN * DIM);
    new_topic_k<<<BATCH * T_LEN, 256, 0, stream>>>(EN, expo, out);
}

// Round 4
// 129.632 us; speedup vs baseline: 1.7432x; 1.0261x over previous
//
#include <hip/hip_runtime.h>
#include <hip/hip_bf16.h>
#include <cstddef>
#include <cstdint>

#define T_LEN 32
#define E_LEN 256
#define BATCH 16
#define DIM 512
#define HID 512
#define WROW 1024  // HID + DIM

#define TWO_LOG2E 2.8853900817779268f  // 2*log2(e)

typedef __attribute__((ext_vector_type(8))) short bf16x8;
typedef __attribute__((ext_vector_type(4))) float f32x4;

__device__ inline bf16x8 cvt8(float4 a, float4 b) {
    union { bf16x8 v; __hip_bfloat16 h[8]; } u;
    u.h[0] = __float2bfloat16(a.x); u.h[1] = __float2bfloat16(a.y);
    u.h[2] = __float2bfloat16(a.z); u.h[3] = __float2bfloat16(a.w);
    u.h[4] = __float2bfloat16(b.x); u.h[5] = __float2bfloat16(b.y);
    u.h[6] = __float2bfloat16(b.z); u.h[7] = __float2bfloat16(b.w);
    return u.v;
}

// ---------------------------------------------------------------------------
// Fused projection GEMM (NT), f32 in -> bf16 MFMA -> f32 out, pre-scaled.
// blockIdx.y < 8: PT' = TWO_LOG2E*(topic @ W[:, :D]^T + b_attn)   (M=512)
// blockIdx.y >= 8: PE' = TWO_LOG2E*(expo @ W[:, D:]^T)            (M=4096)
// Tile 64x64, BK=64, 256 threads, register-double-buffered global loads.
// ---------------------------------------------------------------------------
#define GPAD 8
#define GLDR (64 + GPAD)

__global__ __launch_bounds__(256) void gemm_fused(
    const float* __restrict__ topic, const float* __restrict__ expo,
    const float* __restrict__ W, const float* __restrict__ battn,
    float* __restrict__ PT, float* __restrict__ PE) {
    __shared__ __hip_bfloat16 As[64 * GLDR];
    __shared__ __hip_bfloat16 Bs[64 * GLDR];
    const int tid = threadIdx.x;
    const int by = blockIdx.y;
    const float* A; const float* Wp; const float* bias; float* C; int m0;
    if (by < 8) { A = topic; Wp = W;       bias = battn;   C = PT; m0 = by * 64; }
    else        { A = expo;  Wp = W + DIM; bias = nullptr; C = PE; m0 = (by - 8) * 64; }
    const int n0 = blockIdx.x * 64;
    const int w = tid >> 6;
    const int lane = tid & 63;
    const int l15 = lane & 15;
    const int g = lane >> 4;
    const int srow = tid >> 2;   // 0..63
    const int sc = tid & 3;      // halfword chunks at sc*8 and sc*8+32

    f32x4 acc[4];
    const f32x4 z = {0.f, 0.f, 0.f, 0.f};
#pragma unroll
    for (int nt = 0; nt < 4; ++nt) acc[nt] = z;

    const float* ga = A + (size_t)(m0 + srow) * 512 + sc * 8;
    const float* gb = Wp + (size_t)(n0 + srow) * WROW + sc * 8;

    float4 a0 = *(const float4*)(ga);
    float4 a1 = *(const float4*)(ga + 4);
    float4 a2 = *(const float4*)(ga + 32);
    float4 a3 = *(const float4*)(ga + 36);
    float4 b0 = *(const float4*)(gb);
    float4 b1 = *(const float4*)(gb + 4);
    float4 b2 = *(const float4*)(gb + 32);
    float4 b3 = *(const float4*)(gb + 36);

    for (int kk = 0; kk < 8; ++kk) {
        bf16x8 av0 = cvt8(a0, a1), av1 = cvt8(a2, a3);
        bf16x8 bv0 = cvt8(b0, b1), bv1 = cvt8(b2, b3);
        if (kk < 7) {  // prefetch next K-chunk while this one computes
            ga += 64; gb += 64;
            a0 = *(const float4*)(ga);
            a1 = *(const float4*)(ga + 4);
            a2 = *(const float4*)(ga + 32);
            a3 = *(const float4*)(ga + 36);
            b0 = *(const float4*)(gb);
            b1 = *(const float4*)(gb + 4);
            b2 = *(const float4*)(gb + 32);
            b3 = *(const float4*)(gb + 36);
        }
        __syncthreads();
        *(bf16x8*)&As[srow * GLDR + sc * 8] = av0;
        *(bf16x8*)&As[srow * GLDR + sc * 8 + 32] = av1;
        *(bf16x8*)&Bs[srow * GLDR + sc * 8] = bv0;
        *(bf16x8*)&Bs[srow * GLDR + sc * 8 + 32] = bv1;
        __syncthreads();
#pragma unroll
        for (int s = 0; s < 2; ++s) {
            bf16x8 af = *(const bf16x8*)&As[(w * 16 + l15) * GLDR + (s * 4 + g) * 8];
#pragma unroll
            for (int nt = 0; nt < 4; ++nt) {
                bf16x8 bf = *(const bf16x8*)&Bs[(nt * 16 + l15) * GLDR + (s * 4 + g) * 8];
                acc[nt] = __builtin_amdgcn_mfma_f32_16x16x32_bf16(af, bf, acc[nt], 0, 0, 0);
            }
        }
    }
#pragma unroll
    for (int nt = 0; nt < 4; ++nt) {
        int n = n0 + nt * 16 + l15;
        float bv = bias ? bias[n] : 0.f;
#pragma unroll
        for (int r = 0; r < 4; ++r) {
            int m = m0 + w * 16 + g * 4 + r;
            C[(size_t)m * 512 + n] = (acc[nt][r] + bv) * TWO_LOG2E;
        }
    }
}

// ---------------------------------------------------------------------------
// Energies. PT'/PE' carry the 2*log2e scale, so per element:
// x = pt'+pe'; r = rcp(exp2(x)+1); acc += (-2 v)*r; en = sum(v)+bs+acc.
// Block = (b, 4 t's, 16 e's); wave handles 4 e's x 4 t's. Grid 2048 blocks.
// ---------------------------------------------------------------------------
__global__ __launch_bounds__(256) void energies_k(const float* __restrict__ PT,
                                                  const float* __restrict__ PE,
                                                  const float* __restrict__ v,
                                                  const float* __restrict__ bscore,
                                                  const int* __restrict__ mask,
                                                  float* __restrict__ EN) {
    const int b = blockIdx.x;
    const int tg = blockIdx.y;   // t = tg*4 + i
    const int ech = blockIdx.z;  // e base = ech*16
    const int lane = threadIdx.x & 63;
    const int w = threadIdx.x >> 6;
    const int h0 = lane * 8;

    float sv[8], spt[4][8];
    float sumv;
    {
        float4 v0 = *(const float4*)(v + h0);
        float4 v1 = *(const float4*)(v + h0 + 4);
        float vr[8] = {v0.x, v0.y, v0.z, v0.w, v1.x, v1.y, v1.z, v1.w};
        float s = 0.f;
#pragma unroll
        for (int j = 0; j < 8; ++j) { sv[j] = -2.f * vr[j]; s += vr[j]; }
#pragma unroll
        for (int off = 32; off; off >>= 1) s += __shfl_xor(s, off);
        sumv = s;
#pragma unroll
        for (int i = 0; i < 4; ++i) {
            const float* p = PT + ((size_t)((tg * 4 + i) * BATCH + b)) * HID + h0;
            float4 p0 = *(const float4*)(p);
            float4 p1 = *(const float4*)(p + 4);
            spt[i][0] = p0.x; spt[i][1] = p0.y; spt[i][2] = p0.z; spt[i][3] = p0.w;
            spt[i][4] = p1.x; spt[i][5] = p1.y; spt[i][6] = p1.z; spt[i][7] = p1.w;
        }
    }
    const int e0 = ech * 16 + w * 4;
    const float bs = bscore[0];
#pragma unroll
    for (int ei = 0; ei < 4; ++ei) {
        const int e = e0 + ei;
        const float* pe = PE + ((size_t)(e * BATCH + b)) * HID + h0;
        float4 p0 = *(const float4*)(pe);
        float4 p1 = *(const float4*)(pe + 4);
        float pr[8] = {p0.x, p0.y, p0.z, p0.w, p1.x, p1.y, p1.z, p1.w};
        float acc[4] = {0.f, 0.f, 0.f, 0.f};
#pragma unroll
        for (int i = 0; i < 4; ++i) {
#pragma unroll
            for (int j = 0; j < 8; ++j) {
                float x = spt[i][j] + pr[j];
                float ex = __builtin_amdgcn_exp2f(x);
                float r = __builtin_amdgcn_rcpf(ex + 1.f);
                acc[i] = fmaf(sv[j], r, acc[i]);
            }
        }
#pragma unroll
        for (int i = 0; i < 4; ++i) {
#pragma unroll
            for (int off = 32; off; off >>= 1) acc[i] += __shfl_xor(acc[i], off);
        }
        if (lane == 0) {
            const int msk = mask[e * BATCH + b];
#pragma unroll
            for (int i = 0; i < 4; ++i) {
                float en = sumv + bs + acc[i];
                if (msk != 0) en = -1e12f;
                EN[((size_t)b * T_LEN + tg * 4 + i) * E_LEN + e] = en;
            }
        }
    }
}

// ---------------------------------------------------------------------------
// Fused epilogue.
// blocks [0, 1024):  new_exp[b,e,:] = sum_t softmax_t(EN[b,:,e])[t]*topic[t,b,:]
//                    4 waves/block, one wave per (b,e); dwordx4 loads/stores.
// blocks [1024, 2048): new_topic[b,t,half] = sum_e softmax_e(EN[b,t,:])[e]
//                       * expo[e,b,half*256 + tid];  one block per (b,t,half).
// ---------------------------------------------------------------------------
__global__ __launch_bounds__(256) void epilogue_k(const float* __restrict__ EN,
                                                  const float* __restrict__ topic,
                                                  const float* __restrict__ expo,
                                                  float* __restrict__ out) {
    const int tid = threadIdx.x;
    if (blockIdx.x < 1024) {
        // ---- new_exp: wave per (b,e) ----
        const int idx = blockIdx.x * 4 + (tid >> 6);  // b*E_LEN + e
        const int b = idx >> 8;
        const int e = idx & 255;
        const int lane = tid & 63;
        float x = (lane < T_LEN) ? EN[((size_t)b * T_LEN + lane) * E_LEN + e] : -3e38f;
        float m = x;
#pragma unroll
        for (int off = 16; off; off >>= 1) m = fmaxf(m, __shfl_xor(m, off));
        float p = (lane < T_LEN) ? __expf(x - m) : 0.f;
        float s = p;
#pragma unroll
        for (int off = 16; off; off >>= 1) s += __shfl_xor(s, off);
        float wv = __fdividef(p, s);
        float4 acc0 = {0.f, 0.f, 0.f, 0.f};
        float4 acc1 = {0.f, 0.f, 0.f, 0.f};
        const int d0 = lane * 8;
        for (int t = 0; t < T_LEN; ++t) {
            const float wt = __shfl(wv, t);
            const float* row = topic + ((size_t)t * BATCH + b) * DIM + d0;
            float4 r0 = *(const float4*)(row);
            float4 r1 = *(const float4*)(row + 4);
            acc0.x = fmaf(wt, r0.x, acc0.x); acc0.y = fmaf(wt, r0.y, acc0.y);
            acc0.z = fmaf(wt, r0.z, acc0.z); acc0.w = fmaf(wt, r0.w, acc0.w);
            acc1.x = fmaf(wt, r1.x, acc1.x); acc1.y = fmaf(wt, r1.y, acc1.y);
            acc1.z = fmaf(wt, r1.z, acc1.z); acc1.w = fmaf(wt, r1.w, acc1.w);
        }
        float* o = out + (size_t)BATCH * T_LEN * DIM + ((size_t)b * E_LEN + e) * DIM + d0;
        *(float4*)(o) = acc0;
        *(float4*)(o + 4) = acc1;
    } else {
        // ---- new_topic: block per (b,t,half) ----
        const int q = blockIdx.x - 1024;
        const int bt = q >> 1;         // b*T_LEN + t
        const int half = q & 1;
        __shared__ float wsm[E_LEN];
        __shared__ float wred[4];
        float x = EN[(size_t)bt * E_LEN + tid];
        const int lane = tid & 63;
        const int wid = tid >> 6;
        float m = x;
#pragma unroll
        for (int off = 32; off; off >>= 1) m = fmaxf(m, __shfl_xor(m, off));
        if (lane == 0) wred[wid] = m;
        __syncthreads();
        m = fmaxf(fmaxf(wred[0], wred[1]), fmaxf(wred[2], wred[3]));
        float p = __expf(x - m);
        float s = p;
#pragma unroll
        for (int off = 32; off; off >>= 1) s += __shfl_xor(s, off);
        __syncthreads();
        if (lane == 0) wred[wid] = s;
        __syncthreads();
        s = wred[0] + wred[1] + wred[2] + wred[3];
        wsm[tid] = __fdividef(p, s);
        __syncthreads();
        const int b = bt >> 5;  // bt / T_LEN
        const float* base = expo + half * 256 + tid;
        float acc = 0.f;
#pragma unroll 8
        for (int e = 0; e < E_LEN; ++e) {
            float rv = base[(size_t)(e * BATCH + b) * DIM];
            acc = fmaf(wsm[e], rv, acc);
        }
        out[(size_t)bt * DIM + half * 256 + tid] = acc;
    }
}

extern "C" void kernel_launch(void* const* d_in, const int* in_sizes, int n_in,
                              void* d_out, int out_size, void* d_ws, size_t ws_size,
                              hipStream_t stream) {
    const float* topic = (const float*)d_in[0];   // [T,B,D]
    const float* expo  = (const float*)d_in[1];   // [E,B,D]
    const int*   mask  = (const int*)d_in[2];     // [E,B]
    const float* W     = (const float*)d_in[3];   // [H, H+D]
    const float* battn = (const float*)d_in[4];   // [H]
    const float* vsc   = (const float*)d_in[5];   // [1,H]
    const float* bsc   = (const float*)d_in[6];   // [1]
    float* out = (float*)d_out;                   // new_topic [B,T,D] ++ new_exp [B,E,D]

    float* PT = (float*)d_ws;                     // [512, 512]  1 MB
    float* PE = PT + (size_t)T_LEN * BATCH * HID; // [4096, 512] 8 MB
    float* EN = PE + (size_t)E_LEN * BATCH * HID; // [B,T,E]     0.5 MB

    gemm_fused<<<dim3(8, 72), 256, 0, stream>>>(topic, expo, W, battn, PT, PE);
    energies_k<<<dim3(BATCH, 8, 16), 256, 0, stream>>>(PT, PE, vsc, bsc, mask, EN);
    epilogue_k<<<2048, 256, 0, stream>>>(EN, topic, expo, out);
}

// Round 5
// 120.288 us; speedup vs baseline: 1.8786x; 1.0777x over previous
//
#include <hip/hip_runtime.h>
#include <hip/hip_bf16.h>
#include <cstddef>
#include <cstdint>

#define T_LEN 32
#define E_LEN 256
#define BATCH 16
#define DIM 512
#define HID 512
#define WROW 1024  // HID + DIM

#define TWO_LOG2E 2.8853900817779268f  // 2*log2(e)

typedef __attribute__((ext_vector_type(8))) short bf16x8;
typedef __attribute__((ext_vector_type(4))) float f32x4;

__device__ inline bf16x8 cvt8(float4 a, float4 b) {
    union { bf16x8 v; __hip_bfloat16 h[8]; } u;
    u.h[0] = __float2bfloat16(a.x); u.h[1] = __float2bfloat16(a.y);
    u.h[2] = __float2bfloat16(a.z); u.h[3] = __float2bfloat16(a.w);
    u.h[4] = __float2bfloat16(b.x); u.h[5] = __float2bfloat16(b.y);
    u.h[6] = __float2bfloat16(b.z); u.h[7] = __float2bfloat16(b.w);
    return u.v;
}

// ---------------------------------------------------------------------------
// Fused projection GEMM (NT), f32 in -> bf16 MFMA -> exp2 -> f32 out.
// blockIdx.y < 8:  EPT = 2^(TWO_LOG2E*(topic @ W[:, :D]^T + b_attn))  (M=512)
// blockIdx.y >= 8: EPE = 2^(TWO_LOG2E*(expo @ W[:, D:]^T))            (M=4096)
// so 2^(2log2e*(pt+pe)) = EPT*EPE, letting energies skip exp entirely.
// Tile 64x64, BK=64, 256 threads, register-double-buffered global loads.
// ---------------------------------------------------------------------------
#define GPAD 8
#define GLDR (64 + GPAD)

__global__ __launch_bounds__(256) void gemm_fused(
    const float* __restrict__ topic, const float* __restrict__ expo,
    const float* __restrict__ W, const float* __restrict__ battn,
    float* __restrict__ EPT, float* __restrict__ EPE) {
    __shared__ __hip_bfloat16 As[64 * GLDR];
    __shared__ __hip_bfloat16 Bs[64 * GLDR];
    const int tid = threadIdx.x;
    const int by = blockIdx.y;
    const float* A; const float* Wp; const float* bias; float* C; int m0;
    if (by < 8) { A = topic; Wp = W;       bias = battn;   C = EPT; m0 = by * 64; }
    else        { A = expo;  Wp = W + DIM; bias = nullptr; C = EPE; m0 = (by - 8) * 64; }
    const int n0 = blockIdx.x * 64;
    const int w = tid >> 6;
    const int lane = tid & 63;
    const int l15 = lane & 15;
    const int g = lane >> 4;
    const int srow = tid >> 2;   // 0..63
    const int sc = tid & 3;      // halfword chunks at sc*8 and sc*8+32

    f32x4 acc[4];
    const f32x4 z = {0.f, 0.f, 0.f, 0.f};
#pragma unroll
    for (int nt = 0; nt < 4; ++nt) acc[nt] = z;

    const float* ga = A + (size_t)(m0 + srow) * 512 + sc * 8;
    const float* gb = Wp + (size_t)(n0 + srow) * WROW + sc * 8;

    float4 a0 = *(const float4*)(ga);
    float4 a1 = *(const float4*)(ga + 4);
    float4 a2 = *(const float4*)(ga + 32);
    float4 a3 = *(const float4*)(ga + 36);
    float4 b0 = *(const float4*)(gb);
    float4 b1 = *(const float4*)(gb + 4);
    float4 b2 = *(const float4*)(gb + 32);
    float4 b3 = *(const float4*)(gb + 36);

    for (int kk = 0; kk < 8; ++kk) {
        bf16x8 av0 = cvt8(a0, a1), av1 = cvt8(a2, a3);
        bf16x8 bv0 = cvt8(b0, b1), bv1 = cvt8(b2, b3);
        if (kk < 7) {  // prefetch next K-chunk while this one computes
            ga += 64; gb += 64;
            a0 = *(const float4*)(ga);
            a1 = *(const float4*)(ga + 4);
            a2 = *(const float4*)(ga + 32);
            a3 = *(const float4*)(ga + 36);
            b0 = *(const float4*)(gb);
            b1 = *(const float4*)(gb + 4);
            b2 = *(const float4*)(gb + 32);
            b3 = *(const float4*)(gb + 36);
        }
        __syncthreads();
        *(bf16x8*)&As[srow * GLDR + sc * 8] = av0;
        *(bf16x8*)&As[srow * GLDR + sc * 8 + 32] = av1;
        *(bf16x8*)&Bs[srow * GLDR + sc * 8] = bv0;
        *(bf16x8*)&Bs[srow * GLDR + sc * 8 + 32] = bv1;
        __syncthreads();
#pragma unroll
        for (int s = 0; s < 2; ++s) {
            bf16x8 af = *(const bf16x8*)&As[(w * 16 + l15) * GLDR + (s * 4 + g) * 8];
#pragma unroll
            for (int nt = 0; nt < 4; ++nt) {
                bf16x8 bf = *(const bf16x8*)&Bs[(nt * 16 + l15) * GLDR + (s * 4 + g) * 8];
                acc[nt] = __builtin_amdgcn_mfma_f32_16x16x32_bf16(af, bf, acc[nt], 0, 0, 0);
            }
        }
    }
#pragma unroll
    for (int nt = 0; nt < 4; ++nt) {
        int n = n0 + nt * 16 + l15;
        float bv = bias ? bias[n] : 0.f;
#pragma unroll
        for (int r = 0; r < 4; ++r) {
            int m = m0 + w * 16 + g * 4 + r;
            C[(size_t)m * 512 + n] = __builtin_amdgcn_exp2f((acc[nt][r] + bv) * TWO_LOG2E);
        }
    }
}

// ---------------------------------------------------------------------------
// Energies. EPT/EPE hold 2^(2log2e*proj), so per element (3 instrs, 1 trans):
//   q = fma(ept, epe, 1);  r = rcp(q);  acc = fma(-2v, r, acc)
// EN = sum(v) + b_score + acc.  Block = (b, 4 t's, 16 e's); wave: 4e x 4t.
// ---------------------------------------------------------------------------
__global__ __launch_bounds__(256) void energies_k(const float* __restrict__ EPT,
                                                  const float* __restrict__ EPE,
                                                  const float* __restrict__ v,
                                                  const float* __restrict__ bscore,
                                                  const int* __restrict__ mask,
                                                  float* __restrict__ EN) {
    const int b = blockIdx.x;
    const int tg = blockIdx.y;   // t = tg*4 + i
    const int ech = blockIdx.z;  // e base = ech*16
    const int lane = threadIdx.x & 63;
    const int w = threadIdx.x >> 6;
    const int h0 = lane * 8;

    float sv[8], spt[4][8];
    float sumv;
    {
        float4 v0 = *(const float4*)(v + h0);
        float4 v1 = *(const float4*)(v + h0 + 4);
        float vr[8] = {v0.x, v0.y, v0.z, v0.w, v1.x, v1.y, v1.z, v1.w};
        float s = 0.f;
#pragma unroll
        for (int j = 0; j < 8; ++j) { sv[j] = -2.f * vr[j]; s += vr[j]; }
#pragma unroll
        for (int off = 32; off; off >>= 1) s += __shfl_xor(s, off);
        sumv = s;
#pragma unroll
        for (int i = 0; i < 4; ++i) {
            const float* p = EPT + ((size_t)((tg * 4 + i) * BATCH + b)) * HID + h0;
            float4 p0 = *(const float4*)(p);
            float4 p1 = *(const float4*)(p + 4);
            spt[i][0] = p0.x; spt[i][1] = p0.y; spt[i][2] = p0.z; spt[i][3] = p0.w;
            spt[i][4] = p1.x; spt[i][5] = p1.y; spt[i][6] = p1.z; spt[i][7] = p1.w;
        }
    }
    const int e0 = ech * 16 + w * 4;
    const float bs = bscore[0];
#pragma unroll
    for (int ei = 0; ei < 4; ++ei) {
        const int e = e0 + ei;
        const float* pe = EPE + ((size_t)(e * BATCH + b)) * HID + h0;
        float4 p0 = *(const float4*)(pe);
        float4 p1 = *(const float4*)(pe + 4);
        float pr[8] = {p0.x, p0.y, p0.z, p0.w, p1.x, p1.y, p1.z, p1.w};
        float acc[4] = {0.f, 0.f, 0.f, 0.f};
#pragma unroll
        for (int i = 0; i < 4; ++i) {
#pragma unroll
            for (int j = 0; j < 8; ++j) {
                float q = fmaf(spt[i][j], pr[j], 1.0f);
                float r = __builtin_amdgcn_rcpf(q);
                acc[i] = fmaf(sv[j], r, acc[i]);
            }
        }
#pragma unroll
        for (int i = 0; i < 4; ++i) {
#pragma unroll
            for (int off = 32; off; off >>= 1) acc[i] += __shfl_xor(acc[i], off);
        }
        if (lane == 0) {
            const int msk = mask[e * BATCH + b];
#pragma unroll
            for (int i = 0; i < 4; ++i) {
                float en = sumv + bs + acc[i];
                if (msk != 0) en = -1e12f;
                EN[((size_t)b * T_LEN + tg * 4 + i) * E_LEN + e] = en;
            }
        }
    }
}

// ---------------------------------------------------------------------------
// Fused epilogue, 512 blocks.
// blocks [0,256): new_exp, block=(b, 16 e's), 4 waves x 4 e's. topic_b staged
//   through LDS in 8-row (16 KB) chunks -> topic L2 traffic 268MB -> 16MB.
// blocks [256,512): new_topic, block=(b, 4 t's, d-half). Each expo read is
//   reused across the 4 t's -> expo L2 traffic 268MB -> 67MB.
// ---------------------------------------------------------------------------
__global__ __launch_bounds__(256) void epilogue_k(const float* __restrict__ EN,
                                                  const float* __restrict__ topic,
                                                  const float* __restrict__ expo,
                                                  float* __restrict__ out) {
    __shared__ float smem[4096];  // new_exp: 8x512 topic chunk. new_topic: 4x256 weights.
    const int tid = threadIdx.x;
    const int lane = tid & 63;
    const int w = tid >> 6;
    if (blockIdx.x < 256) {
        // ---- new_exp ----
        const int b = blockIdx.x >> 4;
        const int e0 = (blockIdx.x & 15) * 16 + w * 4;
        float wv[4];
#pragma unroll
        for (int ei = 0; ei < 4; ++ei) {
            const int e = e0 + ei;
            float x = (lane < T_LEN) ? EN[((size_t)b * T_LEN + lane) * E_LEN + e] : -3e38f;
            float m = x;
#pragma unroll
            for (int off = 16; off; off >>= 1) m = fmaxf(m, __shfl_xor(m, off));
            float p = (lane < T_LEN) ? __expf(x - m) : 0.f;
            float s = p;
#pragma unroll
            for (int off = 16; off; off >>= 1) s += __shfl_xor(s, off);
            wv[ei] = __fdividef(p, s);
        }
        float acc[4][8] = {};
        const int d0 = lane * 8;
        for (int tc = 0; tc < 4; ++tc) {
            __syncthreads();
            {   // stage topic rows tc*8 .. tc*8+7 for this b: 16 floats/thread
                int f = tid * 16;
                int r = f >> 9;       // 0..7
                int d = f & 511;
                const float* src = topic + ((size_t)(tc * 8 + r) * BATCH + b) * DIM + d;
                float4 s0 = *(const float4*)(src);
                float4 s1 = *(const float4*)(src + 4);
                float4 s2 = *(const float4*)(src + 8);
                float4 s3 = *(const float4*)(src + 12);
                *(float4*)&smem[r * 512 + d] = s0;
                *(float4*)&smem[r * 512 + d + 4] = s1;
                *(float4*)&smem[r * 512 + d + 8] = s2;
                *(float4*)&smem[r * 512 + d + 12] = s3;
            }
            __syncthreads();
#pragma unroll
            for (int t8 = 0; t8 < 8; ++t8) {
                const int t = tc * 8 + t8;
                float4 r0 = *(const float4*)&smem[t8 * 512 + d0];
                float4 r1 = *(const float4*)&smem[t8 * 512 + d0 + 4];
                float wt[4];
#pragma unroll
                for (int ei = 0; ei < 4; ++ei) wt[ei] = __shfl(wv[ei], t);
#pragma unroll
                for (int ei = 0; ei < 4; ++ei) {
                    acc[ei][0] = fmaf(wt[ei], r0.x, acc[ei][0]);
                    acc[ei][1] = fmaf(wt[ei], r0.y, acc[ei][1]);
                    acc[ei][2] = fmaf(wt[ei], r0.z, acc[ei][2]);
                    acc[ei][3] = fmaf(wt[ei], r0.w, acc[ei][3]);
                    acc[ei][4] = fmaf(wt[ei], r1.x, acc[ei][4]);
                    acc[ei][5] = fmaf(wt[ei], r1.y, acc[ei][5]);
                    acc[ei][6] = fmaf(wt[ei], r1.z, acc[ei][6]);
                    acc[ei][7] = fmaf(wt[ei], r1.w, acc[ei][7]);
                }
            }
        }
#pragma unroll
        for (int ei = 0; ei < 4; ++ei) {
            float* o = out + (size_t)BATCH * T_LEN * DIM +
                       ((size_t)b * E_LEN + e0 + ei) * DIM + d0;
            *(float4*)(o) = *(float4*)&acc[ei][0];
            *(float4*)(o + 4) = *(float4*)&acc[ei][4];
        }
    } else {
        // ---- new_topic ----
        const int q = blockIdx.x - 256;
        const int b = q >> 5;          // 16
        const int tg = (q >> 1) & 15;  // wait: need 8 t-groups x 2 halves
        // layout: q = b*32 + tg*... recompute cleanly below
        const int bq = q >> 5;              // b (q/32) -- 16 b's x 8 tg x 2 half = 256
        const int tg8 = (q >> 2) & 7;       // t-group 0..7
        const int half = q & 1;             // d-half
        // NOTE: bits: q = b*32? 16*8*2 = 256 -> q in [0,256): b = q>>4, tg8=(q>>1)&7, half=q&1
        const int bb = q >> 4;
        const int tgq = (q >> 1) & 7;
        const int hf = q & 1;
        (void)b; (void)tg; (void)bq; (void)tg8; (void)half;
        const int t = tgq * 4 + w;
        const int bt = bb * T_LEN + t;
        // wave softmax over 256 e's (4 per lane)
        float4 xv = *(const float4*)&EN[(size_t)bt * E_LEN + lane * 4];
        float m = fmaxf(fmaxf(xv.x, xv.y), fmaxf(xv.z, xv.w));
#pragma unroll
        for (int off = 32; off; off >>= 1) m = fmaxf(m, __shfl_xor(m, off));
        float p0 = __expf(xv.x - m), p1 = __expf(xv.y - m);
        float p2 = __expf(xv.z - m), p3 = __expf(xv.w - m);
        float s = p0 + p1 + p2 + p3;
#pragma unroll
        for (int off = 32; off; off >>= 1) s += __shfl_xor(s, off);
        float inv = __fdividef(1.f, s);
        float4 wvv = {p0 * inv, p1 * inv, p2 * inv, p3 * inv};
        *(float4*)&smem[w * 256 + lane * 4] = wvv;
        __syncthreads();
        const int dglob = hf * 256 + tid;
        const float* base = expo + (size_t)bb * DIM + dglob;
        float a0 = 0.f, a1 = 0.f, a2 = 0.f, a3 = 0.f;
#pragma unroll 8
        for (int e = 0; e < E_LEN; ++e) {
            float rv = base[(size_t)e * BATCH * DIM];
            a0 = fmaf(smem[e], rv, a0);
            a1 = fmaf(smem[256 + e], rv, a1);
            a2 = fmaf(smem[512 + e], rv, a2);
            a3 = fmaf(smem[768 + e], rv, a3);
        }
        float* o = out + ((size_t)bb * T_LEN + tgq * 4) * DIM + dglob;
        o[0] = a0;
        o[DIM] = a1;
        o[2 * DIM] = a2;
        o[3 * DIM] = a3;
    }
}

extern "C" void kernel_launch(void* const* d_in, const int* in_sizes, int n_in,
                              void* d_out, int out_size, void* d_ws, size_t ws_size,
                              hipStream_t stream) {
    const float* topic = (const float*)d_in[0];   // [T,B,D]
    const float* expo  = (const float*)d_in[1];   // [E,B,D]
    const int*   mask  = (const int*)d_in[2];     // [E,B]
    const float* W     = (const float*)d_in[3];   // [H, H+D]
    const float* battn = (const float*)d_in[4];   // [H]
    const float* vsc   = (const float*)d_in[5];   // [1,H]
    const float* bsc   = (const float*)d_in[6];   // [1]
    float* out = (float*)d_out;                   // new_topic [B,T,D] ++ new_exp [B,E,D]

    float* EPT = (float*)d_ws;                      // [512, 512]  1 MB
    float* EPE = EPT + (size_t)T_LEN * BATCH * HID; // [4096, 512] 8 MB
    float* EN  = EPE + (size_t)E_LEN * BATCH * HID; // [B,T,E]     0.5 MB

    gemm_fused<<<dim3(8, 72), 256, 0, stream>>>(topic, expo, W, battn, EPT, EPE);
    energies_k<<<dim3(BATCH, 8, 16), 256, 0, stream>>>(EPT, EPE, vsc, bsc, mask, EN);
    epilogue_k<<<512, 256, 0, stream>>>(EN, topic, expo, out);
}

// Round 6
// 115.388 us; speedup vs baseline: 1.9583x; 1.0425x over previous
//
#include <hip/hip_runtime.h>
#include <hip/hip_bf16.h>
#include <cstddef>
#include <cstdint>

#define T_LEN 32
#define E_LEN 256
#define BATCH 16
#define DIM 512
#define HID 512
#define WROW 1024  // HID + DIM

#define TWO_LOG2E 2.8853900817779268f  // 2*log2(e)

typedef __attribute__((ext_vector_type(8))) short bf16x8;
typedef __attribute__((ext_vector_type(4))) float f32x4;

__device__ inline bf16x8 cvt8(float4 a, float4 b) {
    union { bf16x8 v; __hip_bfloat16 h[8]; } u;
    u.h[0] = __float2bfloat16(a.x); u.h[1] = __float2bfloat16(a.y);
    u.h[2] = __float2bfloat16(a.z); u.h[3] = __float2bfloat16(a.w);
    u.h[4] = __float2bfloat16(b.x); u.h[5] = __float2bfloat16(b.y);
    u.h[6] = __float2bfloat16(b.z); u.h[7] = __float2bfloat16(b.w);
    return u.v;
}

// ---------------------------------------------------------------------------
// Fused projection GEMM (NT), f32 in -> bf16 MFMA -> exp2 -> f32 out.
// blockIdx.y < 8:  EPT = 2^(TWO_LOG2E*(topic @ W[:, :D]^T + b_attn))  (M=512)
// blockIdx.y >= 8: EPE = 2^(TWO_LOG2E*(expo @ W[:, D:]^T))            (M=4096)
// Tile 64x64, BK=64, 256 threads, register-double-buffered global loads.
// ---------------------------------------------------------------------------
#define GPAD 8
#define GLDR (64 + GPAD)

__global__ __launch_bounds__(256) void gemm_fused(
    const float* __restrict__ topic, const float* __restrict__ expo,
    const float* __restrict__ W, const float* __restrict__ battn,
    float* __restrict__ EPT, float* __restrict__ EPE) {
    __shared__ __hip_bfloat16 As[64 * GLDR];
    __shared__ __hip_bfloat16 Bs[64 * GLDR];
    const int tid = threadIdx.x;
    const int by = blockIdx.y;
    const float* A; const float* Wp; const float* bias; float* C; int m0;
    if (by < 8) { A = topic; Wp = W;       bias = battn;   C = EPT; m0 = by * 64; }
    else        { A = expo;  Wp = W + DIM; bias = nullptr; C = EPE; m0 = (by - 8) * 64; }
    const int n0 = blockIdx.x * 64;
    const int w = tid >> 6;
    const int lane = tid & 63;
    const int l15 = lane & 15;
    const int g = lane >> 4;
    const int srow = tid >> 2;   // 0..63
    const int sc = tid & 3;      // halfword chunks at sc*8 and sc*8+32

    f32x4 acc[4];
    const f32x4 z = {0.f, 0.f, 0.f, 0.f};
#pragma unroll
    for (int nt = 0; nt < 4; ++nt) acc[nt] = z;

    const float* ga = A + (size_t)(m0 + srow) * 512 + sc * 8;
    const float* gb = Wp + (size_t)(n0 + srow) * WROW + sc * 8;

    float4 a0 = *(const float4*)(ga);
    float4 a1 = *(const float4*)(ga + 4);
    float4 a2 = *(const float4*)(ga + 32);
    float4 a3 = *(const float4*)(ga + 36);
    float4 b0 = *(const float4*)(gb);
    float4 b1 = *(const float4*)(gb + 4);
    float4 b2 = *(const float4*)(gb + 32);
    float4 b3 = *(const float4*)(gb + 36);

    for (int kk = 0; kk < 8; ++kk) {
        bf16x8 av0 = cvt8(a0, a1), av1 = cvt8(a2, a3);
        bf16x8 bv0 = cvt8(b0, b1), bv1 = cvt8(b2, b3);
        if (kk < 7) {  // prefetch next K-chunk while this one computes
            ga += 64; gb += 64;
            a0 = *(const float4*)(ga);
            a1 = *(const float4*)(ga + 4);
            a2 = *(const float4*)(ga + 32);
            a3 = *(const float4*)(ga + 36);
            b0 = *(const float4*)(gb);
            b1 = *(const float4*)(gb + 4);
            b2 = *(const float4*)(gb + 32);
            b3 = *(const float4*)(gb + 36);
        }
        __syncthreads();
        *(bf16x8*)&As[srow * GLDR + sc * 8] = av0;
        *(bf16x8*)&As[srow * GLDR + sc * 8 + 32] = av1;
        *(bf16x8*)&Bs[srow * GLDR + sc * 8] = bv0;
        *(bf16x8*)&Bs[srow * GLDR + sc * 8 + 32] = bv1;
        __syncthreads();
#pragma unroll
        for (int s = 0; s < 2; ++s) {
            bf16x8 af = *(const bf16x8*)&As[(w * 16 + l15) * GLDR + (s * 4 + g) * 8];
#pragma unroll
            for (int nt = 0; nt < 4; ++nt) {
                bf16x8 bf = *(const bf16x8*)&Bs[(nt * 16 + l15) * GLDR + (s * 4 + g) * 8];
                acc[nt] = __builtin_amdgcn_mfma_f32_16x16x32_bf16(af, bf, acc[nt], 0, 0, 0);
            }
        }
    }
#pragma unroll
    for (int nt = 0; nt < 4; ++nt) {
        int n = n0 + nt * 16 + l15;
        float bv = bias ? bias[n] : 0.f;
#pragma unroll
        for (int r = 0; r < 4; ++r) {
            int m = m0 + w * 16 + g * 4 + r;
            C[(size_t)m * 512 + n] = __builtin_amdgcn_exp2f((acc[nt][r] + bv) * TWO_LOG2E);
        }
    }
}

// ---------------------------------------------------------------------------
// Energies. EPT/EPE hold 2^(2log2e*proj), so per element (3 instrs, 1 trans):
//   q = fma(ept, epe, 1);  r = rcp(q);  acc = fma(-2v, r, acc)
// EN = sum(v) + b_score + acc.  Masked (e,b) skip all compute (-1e12 direct).
// Block = (b, 4 t's, 16 e's); wave: 4e x 4t.  Grid 2048 blocks.
// ---------------------------------------------------------------------------
__global__ __launch_bounds__(256) void energies_k(const float* __restrict__ EPT,
                                                  const float* __restrict__ EPE,
                                                  const float* __restrict__ v,
                                                  const float* __restrict__ bscore,
                                                  const int* __restrict__ mask,
                                                  float* __restrict__ EN) {
    const int b = blockIdx.x;
    const int tg = blockIdx.y;   // t = tg*4 + i
    const int ech = blockIdx.z;  // e base = ech*16
    const int lane = threadIdx.x & 63;
    const int w = threadIdx.x >> 6;
    const int h0 = lane * 8;
    const int e0 = ech * 16 + w * 4;

    int mk[4];
#pragma unroll
    for (int ei = 0; ei < 4; ++ei) mk[ei] = mask[(e0 + ei) * BATCH + b];

    float sv[8], spt[4][8];
    float sumv;
    {
        float4 v0 = *(const float4*)(v + h0);
        float4 v1 = *(const float4*)(v + h0 + 4);
        float vr[8] = {v0.x, v0.y, v0.z, v0.w, v1.x, v1.y, v1.z, v1.w};
        float s = 0.f;
#pragma unroll
        for (int j = 0; j < 8; ++j) { sv[j] = -2.f * vr[j]; s += vr[j]; }
#pragma unroll
        for (int off = 32; off; off >>= 1) s += __shfl_xor(s, off);
        sumv = s;
#pragma unroll
        for (int i = 0; i < 4; ++i) {
            const float* p = EPT + ((size_t)((tg * 4 + i) * BATCH + b)) * HID + h0;
            float4 p0 = *(const float4*)(p);
            float4 p1 = *(const float4*)(p + 4);
            spt[i][0] = p0.x; spt[i][1] = p0.y; spt[i][2] = p0.z; spt[i][3] = p0.w;
            spt[i][4] = p1.x; spt[i][5] = p1.y; spt[i][6] = p1.z; spt[i][7] = p1.w;
        }
    }
    const float bs = bscore[0];
#pragma unroll
    for (int ei = 0; ei < 4; ++ei) {
        const int e = e0 + ei;
        if (mk[ei] != 0) {  // wave-uniform: skip entire dot product
            if (lane == 0) {
#pragma unroll
                for (int i = 0; i < 4; ++i)
                    EN[((size_t)b * T_LEN + tg * 4 + i) * E_LEN + e] = -1e12f;
            }
            continue;
        }
        const float* pe = EPE + ((size_t)(e * BATCH + b)) * HID + h0;
        float4 p0 = *(const float4*)(pe);
        float4 p1 = *(const float4*)(pe + 4);
        float pr[8] = {p0.x, p0.y, p0.z, p0.w, p1.x, p1.y, p1.z, p1.w};
        float acc[4] = {0.f, 0.f, 0.f, 0.f};
#pragma unroll
        for (int i = 0; i < 4; ++i) {
#pragma unroll
            for (int j = 0; j < 8; ++j) {
                float q = fmaf(spt[i][j], pr[j], 1.0f);
                float r = __builtin_amdgcn_rcpf(q);
                acc[i] = fmaf(sv[j], r, acc[i]);
            }
        }
#pragma unroll
        for (int i = 0; i < 4; ++i) {
#pragma unroll
            for (int off = 32; off; off >>= 1) acc[i] += __shfl_xor(acc[i], off);
        }
        if (lane == 0) {
#pragma unroll
            for (int i = 0; i < 4; ++i) {
                EN[((size_t)b * T_LEN + tg * 4 + i) * E_LEN + e] = sumv + bs + acc[i];
            }
        }
    }
}

// ---------------------------------------------------------------------------
// Fused epilogue, 1024 blocks.
// blocks [0,512): new_exp, block=(b, e-chunk of 16, d-half). Wave handles 4
//   e's: wave softmax over t, then t-loop with direct float4 topic reads
//   (L2-hot: 32 blocks share each b). No LDS, no barriers.
// blocks [512,1024): new_topic, block=(b, t-pair, d-half). Softmax weights
//   for 2 t's in LDS; e-loop split across 4 waves (64 e each, float4/lane);
//   LDS partial reduction at the end.
// ---------------------------------------------------------------------------
__global__ __launch_bounds__(256) void epilogue_k(const float* __restrict__ EN,
                                                  const float* __restrict__ topic,
                                                  const float* __restrict__ expo,
                                                  float* __restrict__ out) {
    __shared__ float smem[2560];  // [0,512): weights; [512,2560): partials
    const int tid = threadIdx.x;
    const int lane = tid & 63;
    const int w = tid >> 6;
    if (blockIdx.x < 512) {
        // ---- new_exp ----
        const int b = blockIdx.x >> 5;
        const int ech = (blockIdx.x >> 1) & 15;
        const int hf = blockIdx.x & 1;
        const int e0 = ech * 16 + w * 4;
        float wv[4];
#pragma unroll
        for (int ei = 0; ei < 4; ++ei) {
            const int e = e0 + ei;
            float x = (lane < T_LEN) ? EN[((size_t)b * T_LEN + lane) * E_LEN + e] : -3e38f;
            float m = x;
#pragma unroll
            for (int off = 16; off; off >>= 1) m = fmaxf(m, __shfl_xor(m, off));
            float p = (lane < T_LEN) ? __expf(x - m) : 0.f;
            float s = p;
#pragma unroll
            for (int off = 16; off; off >>= 1) s += __shfl_xor(s, off);
            wv[ei] = __fdividef(p, s);
        }
        const int d0 = hf * 256 + lane * 4;
        float4 acc[4];
#pragma unroll
        for (int ei = 0; ei < 4; ++ei) acc[ei] = {0.f, 0.f, 0.f, 0.f};
        for (int t = 0; t < T_LEN; ++t) {
            float4 r = *(const float4*)(topic + ((size_t)t * BATCH + b) * DIM + d0);
            float wt[4];
#pragma unroll
            for (int ei = 0; ei < 4; ++ei) wt[ei] = __shfl(wv[ei], t);
#pragma unroll
            for (int ei = 0; ei < 4; ++ei) {
                acc[ei].x = fmaf(wt[ei], r.x, acc[ei].x);
                acc[ei].y = fmaf(wt[ei], r.y, acc[ei].y);
                acc[ei].z = fmaf(wt[ei], r.z, acc[ei].z);
                acc[ei].w = fmaf(wt[ei], r.w, acc[ei].w);
            }
        }
#pragma unroll
        for (int ei = 0; ei < 4; ++ei) {
            float* o = out + (size_t)BATCH * T_LEN * DIM +
                       ((size_t)b * E_LEN + e0 + ei) * DIM + d0;
            *(float4*)o = acc[ei];
        }
    } else {
        // ---- new_topic ----
        const int q = blockIdx.x - 512;
        const int b = q >> 5;           // 16 b
        const int tp = (q >> 1) & 15;   // t-pair: t = tp*2 + {0,1}
        const int hf = q & 1;           // d-half
        // Phase 1: waves 0,1 compute softmax weights for t = tp*2 + w
        if (w < 2) {
            const int bt = b * T_LEN + tp * 2 + w;
            float4 xv = *(const float4*)&EN[(size_t)bt * E_LEN + lane * 4];
            float m = fmaxf(fmaxf(xv.x, xv.y), fmaxf(xv.z, xv.w));
#pragma unroll
            for (int off = 32; off; off >>= 1) m = fmaxf(m, __shfl_xor(m, off));
            float p0 = __expf(xv.x - m), p1 = __expf(xv.y - m);
            float p2 = __expf(xv.z - m), p3 = __expf(xv.w - m);
            float s = p0 + p1 + p2 + p3;
#pragma unroll
            for (int off = 32; off; off >>= 1) s += __shfl_xor(s, off);
            float inv = __fdividef(1.f, s);
            float4 wvv = {p0 * inv, p1 * inv, p2 * inv, p3 * inv};
            *(float4*)&smem[w * 256 + lane * 4] = wvv;
        }
        __syncthreads();
        // Phase 2: wave w handles e in [w*64, w*64+64); lane owns 4 d's.
        const int dl = lane * 4;              // local d within half
        const int dglob = hf * 256 + dl;
        float4 a0 = {0.f, 0.f, 0.f, 0.f};
        float4 a1 = {0.f, 0.f, 0.f, 0.f};
        const float* base = expo + (size_t)b * DIM + dglob;
        for (int ee = 0; ee < 64; ++ee) {
            const int e = w * 64 + ee;
            float4 rv = *(const float4*)(base + (size_t)e * BATCH * DIM);
            float w0 = smem[e];
            float w1 = smem[256 + e];
            a0.x = fmaf(w0, rv.x, a0.x); a0.y = fmaf(w0, rv.y, a0.y);
            a0.z = fmaf(w0, rv.z, a0.z); a0.w = fmaf(w0, rv.w, a0.w);
            a1.x = fmaf(w1, rv.x, a1.x); a1.y = fmaf(w1, rv.y, a1.y);
            a1.z = fmaf(w1, rv.z, a1.z); a1.w = fmaf(w1, rv.w, a1.w);
        }
        *(float4*)&smem[512 + (w * 2 + 0) * 256 + dl] = a0;
        *(float4*)&smem[512 + (w * 2 + 1) * 256 + dl] = a1;
        __syncthreads();
        // Phase 3: 256 threads x 2 outputs: (tt, d=tid)
#pragma unroll
        for (int tt = 0; tt < 2; ++tt) {
            float sum = smem[512 + (0 * 2 + tt) * 256 + tid] +
                        smem[512 + (1 * 2 + tt) * 256 + tid] +
                        smem[512 + (2 * 2 + tt) * 256 + tid] +
                        smem[512 + (3 * 2 + tt) * 256 + tid];
            out[((size_t)b * T_LEN + tp * 2 + tt) * DIM + hf * 256 + tid] = sum;
        }
    }
}

extern "C" void kernel_launch(void* const* d_in, const int* in_sizes, int n_in,
                              void* d_out, int out_size, void* d_ws, size_t ws_size,
                              hipStream_t stream) {
    const float* topic = (const float*)d_in[0];   // [T,B,D]
    const float* expo  = (const float*)d_in[1];   // [E,B,D]
    const int*   mask  = (const int*)d_in[2];     // [E,B]
    const float* W     = (const float*)d_in[3];   // [H, H+D]
    const float* battn = (const float*)d_in[4];   // [H]
    const float* vsc   = (const float*)d_in[5];   // [1,H]
    const float* bsc   = (const float*)d_in[6];   // [1]
    float* out = (float*)d_out;                   // new_topic [B,T,D] ++ new_exp [B,E,D]

    float* EPT = (float*)d_ws;                      // [512, 512]  1 MB
    float* EPE = EPT + (size_t)T_LEN * BATCH * HID; // [4096, 512] 8 MB
    float* EN  = EPE + (size_t)E_LEN * BATCH * HID; // [B,T,E]     0.5 MB

    gemm_fused<<<dim3(8, 72), 256, 0, stream>>>(topic, expo, W, battn, EPT, EPE);
    energies_k<<<dim3(BATCH, 8, 16), 256, 0, stream>>>(EPT, EPE, vsc, bsc, mask, EN);
    epilogue_k<<<1024, 256, 0, stream>>>(EN, topic, expo, out);
}

// Round 9
// 114.504 us; speedup vs baseline: 1.9735x; 1.0077x over previous
//
#include <hip/hip_runtime.h>
#include <hip/hip_bf16.h>
#include <cstddef>
#include <cstdint>

#define T_LEN 32
#define E_LEN 256
#define BATCH 16
#define DIM 512
#define HID 512
#define WROW 1024  // HID + DIM

#define TWO_LOG2E 2.8853900817779268f  // 2*log2(e)
#define LOG2E 1.4426950408889634f

typedef __attribute__((ext_vector_type(8))) short bf16x8;
typedef __attribute__((ext_vector_type(4))) float f32x4;

__device__ inline bf16x8 cvt8(float4 a, float4 b) {
    union { bf16x8 v; __hip_bfloat16 h[8]; } u;
    u.h[0] = __float2bfloat16(a.x); u.h[1] = __float2bfloat16(a.y);
    u.h[2] = __float2bfloat16(a.z); u.h[3] = __float2bfloat16(a.w);
    u.h[4] = __float2bfloat16(b.x); u.h[5] = __float2bfloat16(b.y);
    u.h[6] = __float2bfloat16(b.z); u.h[7] = __float2bfloat16(b.w);
    return u.v;
}

// ---------------------------------------------------------------------------
// Fused projection GEMM (NT), f32 in -> bf16 MFMA -> exp2 -> f32 out.
// blockIdx.y < 8:  EPT = 2^(TWO_LOG2E*(topic @ W[:, :D]^T + b_attn))  (M=512)
// blockIdx.y >= 8: EPE = 2^(TWO_LOG2E*(expo @ W[:, D:]^T))            (M=4096)
// Tile 64x64, BK=64, 256 threads, register-double-buffered global loads.
// ---------------------------------------------------------------------------
#define GPAD 8
#define GLDR (64 + GPAD)

__global__ __launch_bounds__(256) void gemm_fused(
    const float* __restrict__ topic, const float* __restrict__ expo,
    const float* __restrict__ W, const float* __restrict__ battn,
    float* __restrict__ EPT, float* __restrict__ EPE) {
    __shared__ __hip_bfloat16 As[64 * GLDR];
    __shared__ __hip_bfloat16 Bs[64 * GLDR];
    const int tid = threadIdx.x;
    const int by = blockIdx.y;
    const float* A; const float* Wp; const float* bias; float* C; int m0;
    if (by < 8) { A = topic; Wp = W;       bias = battn;   C = EPT; m0 = by * 64; }
    else        { A = expo;  Wp = W + DIM; bias = nullptr; C = EPE; m0 = (by - 8) * 64; }
    const int n0 = blockIdx.x * 64;
    const int w = tid >> 6;
    const int lane = tid & 63;
    const int l15 = lane & 15;
    const int g = lane >> 4;
    const int srow = tid >> 2;   // 0..63
    const int sc = tid & 3;      // halfword chunks at sc*8 and sc*8+32

    f32x4 acc[4];
    const f32x4 z = {0.f, 0.f, 0.f, 0.f};
#pragma unroll
    for (int nt = 0; nt < 4; ++nt) acc[nt] = z;

    const float* ga = A + (size_t)(m0 + srow) * 512 + sc * 8;
    const float* gb = Wp + (size_t)(n0 + srow) * WROW + sc * 8;

    float4 a0 = *(const float4*)(ga);
    float4 a1 = *(const float4*)(ga + 4);
    float4 a2 = *(const float4*)(ga + 32);
    float4 a3 = *(const float4*)(ga + 36);
    float4 b0 = *(const float4*)(gb);
    float4 b1 = *(const float4*)(gb + 4);
    float4 b2 = *(const float4*)(gb + 32);
    float4 b3 = *(const float4*)(gb + 36);

    for (int kk = 0; kk < 8; ++kk) {
        bf16x8 av0 = cvt8(a0, a1), av1 = cvt8(a2, a3);
        bf16x8 bv0 = cvt8(b0, b1), bv1 = cvt8(b2, b3);
        if (kk < 7) {  // prefetch next K-chunk while this one computes
            ga += 64; gb += 64;
            a0 = *(const float4*)(ga);
            a1 = *(const float4*)(ga + 4);
            a2 = *(const float4*)(ga + 32);
            a3 = *(const float4*)(ga + 36);
            b0 = *(const float4*)(gb);
            b1 = *(const float4*)(gb + 4);
            b2 = *(const float4*)(gb + 32);
            b3 = *(const float4*)(gb + 36);
        }
        __syncthreads();
        *(bf16x8*)&As[srow * GLDR + sc * 8] = av0;
        *(bf16x8*)&As[srow * GLDR + sc * 8 + 32] = av1;
        *(bf16x8*)&Bs[srow * GLDR + sc * 8] = bv0;
        *(bf16x8*)&Bs[srow * GLDR + sc * 8 + 32] = bv1;
        __syncthreads();
#pragma unroll
        for (int s = 0; s < 2; ++s) {
            bf16x8 af = *(const bf16x8*)&As[(w * 16 + l15) * GLDR + (s * 4 + g) * 8];
#pragma unroll
            for (int nt = 0; nt < 4; ++nt) {
                bf16x8 bf = *(const bf16x8*)&Bs[(nt * 16 + l15) * GLDR + (s * 4 + g) * 8];
                acc[nt] = __builtin_amdgcn_mfma_f32_16x16x32_bf16(af, bf, acc[nt], 0, 0, 0);
            }
        }
    }
#pragma unroll
    for (int nt = 0; nt < 4; ++nt) {
        int n = n0 + nt * 16 + l15;
        float bv = bias ? bias[n] : 0.f;
#pragma unroll
        for (int r = 0; r < 4; ++r) {
            int m = m0 + w * 16 + g * 4 + r;
            C[(size_t)m * 512 + n] = __builtin_amdgcn_exp2f((acc[nt][r] + bv) * TWO_LOG2E);
        }
    }
}

// ---------------------------------------------------------------------------
// Energies -> writes P = exp(acc), where acc = energy minus the constant
// (sum(v)+b_score), which cancels in both softmaxes. Masked (e,b) -> P=1e-30
// (softmax-over-t of all-masked column = uniform 1/32, matching reference;
// negligible in softmax-over-e).
// Per element: q = fma(ept, epe, 1); r = rcp(q); acc = fma(-2v, r, acc).
// Block = (b, 8 t's, 16 e's); wave: 4 e's x 8 t's. Grid (16,4,16)=1024.
// Reduction: butterfly{1,2,4,8} per acc, select-trick + {16,32} per group.
// ---------------------------------------------------------------------------
__global__ __launch_bounds__(256) void energies_k(const float* __restrict__ EPT,
                                                  const float* __restrict__ EPE,
                                                  const float* __restrict__ v,
                                                  const int* __restrict__ mask,
                                                  float* __restrict__ P) {
    const int b = blockIdx.x;    // 16
    const int tg = blockIdx.y;   // 4: t = tg*8 + i
    const int ech = blockIdx.z;  // 16: e base = ech*16
    const int lane = threadIdx.x & 63;
    const int w = threadIdx.x >> 6;
    const int h0 = lane * 8;
    const int e0 = ech * 16 + w * 4;

    int mk[4];
#pragma unroll
    for (int ei = 0; ei < 4; ++ei) mk[ei] = mask[(e0 + ei) * BATCH + b];

    float sv[8], spt[8][8];
    {
        float4 v0 = *(const float4*)(v + h0);
        float4 v1 = *(const float4*)(v + h0 + 4);
        sv[0] = -2.f * v0.x; sv[1] = -2.f * v0.y; sv[2] = -2.f * v0.z; sv[3] = -2.f * v0.w;
        sv[4] = -2.f * v1.x; sv[5] = -2.f * v1.y; sv[6] = -2.f * v1.z; sv[7] = -2.f * v1.w;
#pragma unroll
        for (int i = 0; i < 8; ++i) {
            const float* p = EPT + ((size_t)((tg * 8 + i) * BATCH + b)) * HID + h0;
            float4 p0 = *(const float4*)(p);
            float4 p1 = *(const float4*)(p + 4);
            spt[i][0] = p0.x; spt[i][1] = p0.y; spt[i][2] = p0.z; spt[i][3] = p0.w;
            spt[i][4] = p1.x; spt[i][5] = p1.y; spt[i][6] = p1.z; spt[i][7] = p1.w;
        }
    }
#pragma unroll
    for (int ei = 0; ei < 4; ++ei) {
        const int e = e0 + ei;
        if (mk[ei] != 0) {  // wave-uniform skip
            if (lane < 8)
                P[((size_t)b * T_LEN + tg * 8 + lane) * E_LEN + e] = 1e-30f;
            continue;
        }
        const float* pe = EPE + ((size_t)(e * BATCH + b)) * HID + h0;
        float4 p0 = *(const float4*)(pe);
        float4 p1 = *(const float4*)(pe + 4);
        float pr[8] = {p0.x, p0.y, p0.z, p0.w, p1.x, p1.y, p1.z, p1.w};
        float a[8] = {0.f, 0.f, 0.f, 0.f, 0.f, 0.f, 0.f, 0.f};
#pragma unroll
        for (int i = 0; i < 8; ++i) {
#pragma unroll
            for (int j = 0; j < 8; ++j) {
                float q = fmaf(spt[i][j], pr[j], 1.0f);
                float r = __builtin_amdgcn_rcpf(q);
                a[i] = fmaf(sv[j], r, a[i]);
            }
        }
        // reduce: within 16-lane groups for all 8 accs
#pragma unroll
        for (int i = 0; i < 8; ++i) {
            a[i] += __shfl_xor(a[i], 1);
            a[i] += __shfl_xor(a[i], 2);
            a[i] += __shfl_xor(a[i], 4);
            a[i] += __shfl_xor(a[i], 8);
        }
        // select-trick: lane picks acc_{lane&3} of each group, sum across groups
        const int sel = lane & 3;
        float uA = sel == 0 ? a[0] : sel == 1 ? a[1] : sel == 2 ? a[2] : a[3];
        float uB = sel == 0 ? a[4] : sel == 1 ? a[5] : sel == 2 ? a[6] : a[7];
        uA += __shfl_xor(uA, 16); uA += __shfl_xor(uA, 32);
        uB += __shfl_xor(uB, 16); uB += __shfl_xor(uB, 32);
        // lane l in [0,8): total for t = tg*8 + l
        float u = (lane & 4) ? uB : uA;
        if (lane < 8)
            P[((size_t)b * T_LEN + tg * 8 + lane) * E_LEN + e] =
                __builtin_amdgcn_exp2f(u * LOG2E);
    }
}

// ---------------------------------------------------------------------------
// Fused epilogue on P (no max pass, no exp).
// blocks [0,512): new_exp, block=(b, e-chunk of 16, d-half). Wave: 4 e's;
//   w_t = P_t / sum_t P; t-loop with float4 topic reads.
// blocks [512,1024): new_topic, block=(b, t-pair, d-half). w_e = P_e / sum_e;
//   e-loop split across 4 waves; LDS partial reduction.
// ---------------------------------------------------------------------------
__global__ __launch_bounds__(256) void epilogue_k(const float* __restrict__ P,
                                                  const float* __restrict__ topic,
                                                  const float* __restrict__ expo,
                                                  float* __restrict__ out) {
    __shared__ float smem[2560];  // [0,512): weights; [512,2560): partials
    const int tid = threadIdx.x;
    const int lane = tid & 63;
    const int w = tid >> 6;
    if (blockIdx.x < 512) {
        // ---- new_exp ----
        const int b = blockIdx.x >> 5;
        const int ech = (blockIdx.x >> 1) & 15;
        const int hf = blockIdx.x & 1;
        const int e0 = ech * 16 + w * 4;
        float wv[4];
#pragma unroll
        for (int ei = 0; ei < 4; ++ei) {
            const int e = e0 + ei;
            float x = (lane < T_LEN) ? P[((size_t)b * T_LEN + lane) * E_LEN + e] : 0.f;
            float s = x;
#pragma unroll
            for (int off = 32; off; off >>= 1) s += __shfl_xor(s, off);
            wv[ei] = x * __builtin_amdgcn_rcpf(s);
        }
        const int d0 = hf * 256 + lane * 4;
        float4 acc[4];
#pragma unroll
        for (int ei = 0; ei < 4; ++ei) acc[ei] = {0.f, 0.f, 0.f, 0.f};
        for (int t = 0; t < T_LEN; ++t) {
            float4 r = *(const float4*)(topic + ((size_t)t * BATCH + b) * DIM + d0);
            float wt[4];
#pragma unroll
            for (int ei = 0; ei < 4; ++ei) wt[ei] = __shfl(wv[ei], t);
#pragma unroll
            for (int ei = 0; ei < 4; ++ei) {
                acc[ei].x = fmaf(wt[ei], r.x, acc[ei].x);
                acc[ei].y = fmaf(wt[ei], r.y, acc[ei].y);
                acc[ei].z = fmaf(wt[ei], r.z, acc[ei].z);
                acc[ei].w = fmaf(wt[ei], r.w, acc[ei].w);
            }
        }
#pragma unroll
        for (int ei = 0; ei < 4; ++ei) {
            float* o = out + (size_t)BATCH * T_LEN * DIM +
                       ((size_t)b * E_LEN + e0 + ei) * DIM + d0;
            *(float4*)o = acc[ei];
        }
    } else {
        // ---- new_topic ----
        const int q = blockIdx.x - 512;
        const int b = q >> 5;           // 16 b
        const int tp = (q >> 1) & 15;   // t-pair: t = tp*2 + {0,1}
        const int hf = q & 1;           // d-half
        // Phase 1: waves 0,1 compute softmax weights for t = tp*2 + w
        if (w < 2) {
            const int bt = b * T_LEN + tp * 2 + w;
            float4 xv = *(const float4*)&P[(size_t)bt * E_LEN + lane * 4];
            float s = xv.x + xv.y + xv.z + xv.w;
#pragma unroll
            for (int off = 32; off; off >>= 1) s += __shfl_xor(s, off);
            float inv = __builtin_amdgcn_rcpf(s);
            float4 wvv = {xv.x * inv, xv.y * inv, xv.z * inv, xv.w * inv};
            *(float4*)&smem[w * 256 + lane * 4] = wvv;
        }
        __syncthreads();
        // Phase 2: wave w handles e in [w*64, w*64+64); lane owns 4 d's.
        const int dl = lane * 4;
        const int dglob = hf * 256 + dl;
        float4 a0 = {0.f, 0.f, 0.f, 0.f};
        float4 a1 = {0.f, 0.f, 0.f, 0.f};
        const float* base = expo + (size_t)b * DIM + dglob;
        for (int ee = 0; ee < 64; ++ee) {
            const int e = w * 64 + ee;
            float4 rv = *(const float4*)(base + (size_t)e * BATCH * DIM);
            float w0 = smem[e];
            float w1 = smem[256 + e];
            a0.x = fmaf(w0, rv.x, a0.x); a0.y = fmaf(w0, rv.y, a0.y);
            a0.z = fmaf(w0, rv.z, a0.z); a0.w = fmaf(w0, rv.w, a0.w);
            a1.x = fmaf(w1, rv.x, a1.x); a1.y = fmaf(w1, rv.y, a1.y);
            a1.z = fmaf(w1, rv.z, a1.z); a1.w = fmaf(w1, rv.w, a1.w);
        }
        *(float4*)&smem[512 + (w * 2 + 0) * 256 + dl] = a0;
        *(float4*)&smem[512 + (w * 2 + 1) * 256 + dl] = a1;
        __syncthreads();
        // Phase 3: 256 threads x 2 outputs: (tt, d=tid)
#pragma unroll
        for (int tt = 0; tt < 2; ++tt) {
            float sum = smem[512 + (0 * 2 + tt) * 256 + tid] +
                        smem[512 + (1 * 2 + tt) * 256 + tid] +
                        smem[512 + (2 * 2 + tt) * 256 + tid] +
                        smem[512 + (3 * 2 + tt) * 256 + tid];
            out[((size_t)b * T_LEN + tp * 2 + tt) * DIM + hf * 256 + tid] = sum;
        }
    }
}

extern "C" void kernel_launch(void* const* d_in, const int* in_sizes, int n_in,
                              void* d_out, int out_size, void* d_ws, size_t ws_size,
                              hipStream_t stream) {
    const float* topic = (const float*)d_in[0];   // [T,B,D]
    const float* expo  = (const float*)d_in[1];   // [E,B,D]
    const int*   mask  = (const int*)d_in[2];     // [E,B]
    const float* W     = (const float*)d_in[3];   // [H, H+D]
    const float* battn = (const float*)d_in[4];   // [H]
    const float* vsc   = (const float*)d_in[5];   // [1,H]
    float* out = (float*)d_out;                   // new_topic [B,T,D] ++ new_exp [B,E,D]

    float* EPT = (float*)d_ws;                      // [512, 512]  1 MB
    float* EPE = EPT + (size_t)T_LEN * BATCH * HID; // [4096, 512] 8 MB
    float* P   = EPE + (size_t)E_LEN * BATCH * HID; // [B,T,E]     0.5 MB

    gemm_fused<<<dim3(8, 72), 256, 0, stream>>>(topic, expo, W, battn, EPT, EPE);
    energies_k<<<dim3(BATCH, 4, 16), 256, 0, stream>>>(EPT, EPE, vsc, mask, P);
    epilogue_k<<<1024, 256, 0, stream>>>(P, topic, expo, out);
}

// Round 12
// 113.867 us; speedup vs baseline: 1.9845x; 1.0056x over previous
//
#include <hip/hip_runtime.h>
#include <hip/hip_bf16.h>
#include <cstddef>
#include <cstdint>

#define T_LEN 32
#define E_LEN 256
#define BATCH 16
#define DIM 512
#define HID 512
#define WROW 1024  // HID + DIM

#define TWO_LOG2E 2.8853900817779268f  // 2*log2(e)
#define LOG2E 1.4426950408889634f

typedef __attribute__((ext_vector_type(8))) short bf16x8;
typedef __attribute__((ext_vector_type(4))) float f32x4;

__device__ inline bf16x8 cvt8(float4 a, float4 b) {
    union { bf16x8 v; __hip_bfloat16 h[8]; } u;
    u.h[0] = __float2bfloat16(a.x); u.h[1] = __float2bfloat16(a.y);
    u.h[2] = __float2bfloat16(a.z); u.h[3] = __float2bfloat16(a.w);
    u.h[4] = __float2bfloat16(b.x); u.h[5] = __float2bfloat16(b.y);
    u.h[6] = __float2bfloat16(b.z); u.h[7] = __float2bfloat16(b.w);
    return u.v;
}

#define GPAD 8
#define GLDR (64 + GPAD)   // 72 halfwords per LDS row

// ---------------------------------------------------------------------------
// Fused projection GEMM (NT), f32 in -> bf16 MFMA -> exp2 -> out.
// blk < 64:  EPT(f32)  = 2^(TWO_LOG2E*(topic @ W[:,:D]^T + b_attn))  (M=512)
// blk >= 64: EPE(bf16) = 2^(TWO_LOG2E*(expo @ W[:,D:]^T))            (M=4096)
// Tile 64x64, BK=64, 256 threads, register-double-buffered global loads.
// ---------------------------------------------------------------------------
__global__ __launch_bounds__(256) void gemm_fused_k(
    const float* __restrict__ topic, const float* __restrict__ expo,
    const float* __restrict__ W, const float* __restrict__ battn,
    float* __restrict__ EPT, __hip_bfloat16* __restrict__ EPE) {
    __shared__ __hip_bfloat16 As[64 * GLDR];
    __shared__ __hip_bfloat16 Bs[64 * GLDR];
    const int tid = threadIdx.x;
    const int by = blockIdx.x >> 3;       // 0..71
    const int n0 = (blockIdx.x & 7) * 64;
    const float* A; const float* Wp; int m0;
    const bool isT = (by < 8);
    if (isT) { A = topic; Wp = W;       m0 = by * 64; }
    else     { A = expo;  Wp = W + DIM; m0 = (by - 8) * 64; }
    const int w = tid >> 6;
    const int lane = tid & 63;
    const int l15 = lane & 15;
    const int g = lane >> 4;
    const int srow = tid >> 2;   // 0..63
    const int sc = tid & 3;      // halfword chunks at sc*8 and sc*8+32

    f32x4 acc[4];
    const f32x4 z = {0.f, 0.f, 0.f, 0.f};
#pragma unroll
    for (int nt = 0; nt < 4; ++nt) acc[nt] = z;

    const float* ga = A + (size_t)(m0 + srow) * 512 + sc * 8;
    const float* gb = Wp + (size_t)(n0 + srow) * WROW + sc * 8;

    float4 a0 = *(const float4*)(ga);
    float4 a1 = *(const float4*)(ga + 4);
    float4 a2 = *(const float4*)(ga + 32);
    float4 a3 = *(const float4*)(ga + 36);
    float4 b0 = *(const float4*)(gb);
    float4 b1 = *(const float4*)(gb + 4);
    float4 b2 = *(const float4*)(gb + 32);
    float4 b3 = *(const float4*)(gb + 36);

    for (int kk = 0; kk < 8; ++kk) {
        bf16x8 av0 = cvt8(a0, a1), av1 = cvt8(a2, a3);
        bf16x8 bv0 = cvt8(b0, b1), bv1 = cvt8(b2, b3);
        if (kk < 7) {  // prefetch next K-chunk while this one computes
            ga += 64; gb += 64;
            a0 = *(const float4*)(ga);
            a1 = *(const float4*)(ga + 4);
            a2 = *(const float4*)(ga + 32);
            a3 = *(const float4*)(ga + 36);
            b0 = *(const float4*)(gb);
            b1 = *(const float4*)(gb + 4);
            b2 = *(const float4*)(gb + 32);
            b3 = *(const float4*)(gb + 36);
        }
        __syncthreads();
        *(bf16x8*)&As[srow * GLDR + sc * 8] = av0;
        *(bf16x8*)&As[srow * GLDR + sc * 8 + 32] = av1;
        *(bf16x8*)&Bs[srow * GLDR + sc * 8] = bv0;
        *(bf16x8*)&Bs[srow * GLDR + sc * 8 + 32] = bv1;
        __syncthreads();
#pragma unroll
        for (int s = 0; s < 2; ++s) {
            bf16x8 af = *(const bf16x8*)&As[(w * 16 + l15) * GLDR + (s * 4 + g) * 8];
#pragma unroll
            for (int nt = 0; nt < 4; ++nt) {
                bf16x8 bf = *(const bf16x8*)&Bs[(nt * 16 + l15) * GLDR + (s * 4 + g) * 8];
                acc[nt] = __builtin_amdgcn_mfma_f32_16x16x32_bf16(af, bf, acc[nt], 0, 0, 0);
            }
        }
    }
    if (isT) {
#pragma unroll
        for (int nt = 0; nt < 4; ++nt) {
            int n = n0 + nt * 16 + l15;
            float bv = battn[n];
#pragma unroll
            for (int r = 0; r < 4; ++r) {
                int m = m0 + w * 16 + g * 4 + r;
                EPT[(size_t)m * 512 + n] =
                    __builtin_amdgcn_exp2f((acc[nt][r] + bv) * TWO_LOG2E);
            }
        }
    } else {
#pragma unroll
        for (int nt = 0; nt < 4; ++nt) {
            int n = n0 + nt * 16 + l15;
#pragma unroll
            for (int r = 0; r < 4; ++r) {
                int m = m0 + w * 16 + g * 4 + r;
                EPE[(size_t)m * 512 + n] = __float2bfloat16(
                    __builtin_amdgcn_exp2f(acc[nt][r] * TWO_LOG2E));
            }
        }
    }
}

// ---------------------------------------------------------------------------
// Energies -> P = exp(energy - const(sum v + b_score)); masked -> 1e-30.
// EPE is bf16 (half the read traffic); EPT f32.
// Per element: q = fma(ept, epe, 1); r = rcp(q); acc = fma(-2v, r, acc).
// Block = (b, 8 t's, 16 e's); wave: 4 e's x 8 t's. Grid 1024.
// ---------------------------------------------------------------------------
__global__ __launch_bounds__(256) void energies_k(
    const float* __restrict__ EPT, const __hip_bfloat16* __restrict__ EPE,
    const float* __restrict__ v, const int* __restrict__ mask,
    float* __restrict__ P) {
    const int u = blockIdx.x;
    const int b = u & 15;
    const int tg = (u >> 4) & 3;   // t = tg*8 + i
    const int ech = u >> 6;        // e base = ech*16
    const int tid = threadIdx.x;
    const int lane = tid & 63;
    const int w = tid >> 6;
    const int h0 = lane * 8;
    const int e0 = ech * 16 + w * 4;

    int mk[4];
#pragma unroll
    for (int ei = 0; ei < 4; ++ei) mk[ei] = mask[(e0 + ei) * BATCH + b];

    float sv[8], spt[8][8];
    {
        float4 v0 = *(const float4*)(v + h0);
        float4 v1 = *(const float4*)(v + h0 + 4);
        sv[0] = -2.f * v0.x; sv[1] = -2.f * v0.y; sv[2] = -2.f * v0.z; sv[3] = -2.f * v0.w;
        sv[4] = -2.f * v1.x; sv[5] = -2.f * v1.y; sv[6] = -2.f * v1.z; sv[7] = -2.f * v1.w;
#pragma unroll
        for (int i = 0; i < 8; ++i) {
            const float* p = EPT + ((size_t)((tg * 8 + i) * BATCH + b)) * HID + h0;
            float4 p0 = *(const float4*)(p);
            float4 p1 = *(const float4*)(p + 4);
            spt[i][0] = p0.x; spt[i][1] = p0.y; spt[i][2] = p0.z; spt[i][3] = p0.w;
            spt[i][4] = p1.x; spt[i][5] = p1.y; spt[i][6] = p1.z; spt[i][7] = p1.w;
        }
    }
#pragma unroll
    for (int ei = 0; ei < 4; ++ei) {
        const int e = e0 + ei;
        if (mk[ei] != 0) {  // wave-uniform skip
            if (lane < 8)
                P[((size_t)b * T_LEN + tg * 8 + lane) * E_LEN + e] = 1e-30f;
            continue;
        }
        union { bf16x8 v8; __hip_bfloat16 h[8]; } pv;
        pv.v8 = *(const bf16x8*)(EPE + ((size_t)(e * BATCH + b)) * HID + h0);
        float pr[8];
#pragma unroll
        for (int j = 0; j < 8; ++j) pr[j] = __bfloat162float(pv.h[j]);
        float a[8] = {0.f, 0.f, 0.f, 0.f, 0.f, 0.f, 0.f, 0.f};
#pragma unroll
        for (int i = 0; i < 8; ++i) {
#pragma unroll
            for (int j = 0; j < 8; ++j) {
                float q = fmaf(spt[i][j], pr[j], 1.0f);
                float r = __builtin_amdgcn_rcpf(q);
                a[i] = fmaf(sv[j], r, a[i]);
            }
        }
#pragma unroll
        for (int i = 0; i < 8; ++i) {
            a[i] += __shfl_xor(a[i], 1);
            a[i] += __shfl_xor(a[i], 2);
            a[i] += __shfl_xor(a[i], 4);
            a[i] += __shfl_xor(a[i], 8);
        }
        const int sel = lane & 3;
        float uA = sel == 0 ? a[0] : sel == 1 ? a[1] : sel == 2 ? a[2] : a[3];
        float uB = sel == 0 ? a[4] : sel == 1 ? a[5] : sel == 2 ? a[6] : a[7];
        uA += __shfl_xor(uA, 16); uA += __shfl_xor(uA, 32);
        uB += __shfl_xor(uB, 16); uB += __shfl_xor(uB, 32);
        float uu = (lane & 4) ? uB : uA;
        if (lane < 8)
            P[((size_t)b * T_LEN + tg * 8 + lane) * E_LEN + e] =
                __builtin_amdgcn_exp2f(uu * LOG2E);
    }
}

// ---------------------------------------------------------------------------
// Fused epilogue on P, 768 blocks.
// blocks [0,512): new_exp, block=(b, e-chunk of 16, d-half). Wave: 4 e's.
// blocks [512,768): new_topic, block=(b, t-quad, d-half): weights for 4 t's
//   (one per wave) in LDS; e-loop sliced across waves (64 e each) with 4-t
//   register accumulators; LDS partial reduction. Expo traffic 64 MB total.
// ---------------------------------------------------------------------------
__global__ __launch_bounds__(256) void epilogue_k(
    const float* __restrict__ P, const float* __restrict__ topic,
    const float* __restrict__ expo, float* __restrict__ out) {
    __shared__ float smem[5120];  // [0,1024): weights; [1024,5120): partials
    const int tid = threadIdx.x;
    const int lane = tid & 63;
    const int w = tid >> 6;
    if (blockIdx.x < 512) {
        // ---- new_exp ----
        const int b = blockIdx.x >> 5;
        const int ech = (blockIdx.x >> 1) & 15;
        const int hf = blockIdx.x & 1;
        const int e0 = ech * 16 + w * 4;
        float wv[4];
#pragma unroll
        for (int ei = 0; ei < 4; ++ei) {
            const int e = e0 + ei;
            float x = (lane < T_LEN) ? P[((size_t)b * T_LEN + lane) * E_LEN + e] : 0.f;
            float s = x;
#pragma unroll
            for (int off = 32; off; off >>= 1) s += __shfl_xor(s, off);
            wv[ei] = x * __builtin_amdgcn_rcpf(s);
        }
        const int d0 = hf * 256 + lane * 4;
        float4 acc[4];
#pragma unroll
        for (int ei = 0; ei < 4; ++ei) acc[ei] = {0.f, 0.f, 0.f, 0.f};
        for (int t = 0; t < T_LEN; ++t) {
            float4 r = *(const float4*)(topic + ((size_t)t * BATCH + b) * DIM + d0);
            float wt[4];
#pragma unroll
            for (int ei = 0; ei < 4; ++ei) wt[ei] = __shfl(wv[ei], t);
#pragma unroll
            for (int ei = 0; ei < 4; ++ei) {
                acc[ei].x = fmaf(wt[ei], r.x, acc[ei].x);
                acc[ei].y = fmaf(wt[ei], r.y, acc[ei].y);
                acc[ei].z = fmaf(wt[ei], r.z, acc[ei].z);
                acc[ei].w = fmaf(wt[ei], r.w, acc[ei].w);
            }
        }
#pragma unroll
        for (int ei = 0; ei < 4; ++ei) {
            float* o = out + (size_t)BATCH * T_LEN * DIM +
                       ((size_t)b * E_LEN + e0 + ei) * DIM + d0;
            *(float4*)o = acc[ei];
        }
    } else {
        // ---- new_topic (t-quad) ----
        const int q = blockIdx.x - 512;   // [0,256)
        const int b = q >> 4;             // 16 b
        const int tq = (q >> 1) & 7;      // t-quad: t = tq*4 + {0..3}
        const int hf = q & 1;             // d-half
        // Phase 1: wave w computes softmax weights for t = tq*4 + w
        {
            const int bt = b * T_LEN + tq * 4 + w;
            float4 xv = *(const float4*)&P[(size_t)bt * E_LEN + lane * 4];
            float s = xv.x + xv.y + xv.z + xv.w;
#pragma unroll
            for (int off = 32; off; off >>= 1) s += __shfl_xor(s, off);
            float inv = __builtin_amdgcn_rcpf(s);
            float4 wvv = {xv.x * inv, xv.y * inv, xv.z * inv, xv.w * inv};
            *(float4*)&smem[w * 256 + lane * 4] = wvv;
        }
        __syncthreads();
        // Phase 2: wave w handles e in [w*64, w*64+64); lane owns 4 d's;
        // accumulates all 4 t's (each expo read reused 4x).
        const int dl = lane * 4;
        const int dglob = hf * 256 + dl;
        float4 a0 = {0.f, 0.f, 0.f, 0.f};
        float4 a1 = {0.f, 0.f, 0.f, 0.f};
        float4 a2 = {0.f, 0.f, 0.f, 0.f};
        float4 a3 = {0.f, 0.f, 0.f, 0.f};
        const float* base = expo + (size_t)b * DIM + dglob;
        for (int ee = 0; ee < 64; ++ee) {
            const int e = w * 64 + ee;
            float4 rv = *(const float4*)(base + (size_t)e * BATCH * DIM);
            float w0 = smem[e];
            float w1 = smem[256 + e];
            float w2 = smem[512 + e];
            float w3 = smem[768 + e];
            a0.x = fmaf(w0, rv.x, a0.x); a0.y = fmaf(w0, rv.y, a0.y);
            a0.z = fmaf(w0, rv.z, a0.z); a0.w = fmaf(w0, rv.w, a0.w);
            a1.x = fmaf(w1, rv.x, a1.x); a1.y = fmaf(w1, rv.y, a1.y);
            a1.z = fmaf(w1, rv.z, a1.z); a1.w = fmaf(w1, rv.w, a1.w);
            a2.x = fmaf(w2, rv.x, a2.x); a2.y = fmaf(w2, rv.y, a2.y);
            a2.z = fmaf(w2, rv.z, a2.z); a2.w = fmaf(w2, rv.w, a2.w);
            a3.x = fmaf(w3, rv.x, a3.x); a3.y = fmaf(w3, rv.y, a3.y);
            a3.z = fmaf(w3, rv.z, a3.z); a3.w = fmaf(w3, rv.w, a3.w);
        }
        // partials: [wave][t][256 d]
        *(float4*)&smem[1024 + (w * 4 + 0) * 256 + dl] = a0;
        *(float4*)&smem[1024 + (w * 4 + 1) * 256 + dl] = a1;
        *(float4*)&smem[1024 + (w * 4 + 2) * 256 + dl] = a2;
        *(float4*)&smem[1024 + (w * 4 + 3) * 256 + dl] = a3;
        __syncthreads();
        // Phase 3: 256 threads x 4 outputs: (tt, d=tid)
#pragma unroll
        for (int tt = 0; tt < 4; ++tt) {
            float sum = smem[1024 + (0 * 4 + tt) * 256 + tid] +
                        smem[1024 + (1 * 4 + tt) * 256 + tid] +
                        smem[1024 + (2 * 4 + tt) * 256 + tid] +
                        smem[1024 + (3 * 4 + tt) * 256 + tid];
            out[((size_t)b * T_LEN + tq * 4 + tt) * DIM + hf * 256 + tid] = sum;
        }
    }
}

extern "C" void kernel_launch(void* const* d_in, const int* in_sizes, int n_in,
                              void* d_out, int out_size, void* d_ws, size_t ws_size,
                              hipStream_t stream) {
    const float* topic = (const float*)d_in[0];   // [T,B,D]
    const float* expo  = (const float*)d_in[1];   // [E,B,D]
    const int*   mask  = (const int*)d_in[2];     // [E,B]
    const float* W     = (const float*)d_in[3];   // [H, H+D]
    const float* battn = (const float*)d_in[4];   // [H]
    const float* vsc   = (const float*)d_in[5];   // [1,H]
    float* out = (float*)d_out;                   // new_topic [B,T,D] ++ new_exp [B,E,D]

    float* EPT = (float*)d_ws;                               // [512,512] f32, 1 MB
    __hip_bfloat16* EPE = (__hip_bfloat16*)(EPT + 512 * 512); // [4096,512] bf16, 4 MB
    float* P = (float*)(EPE + (size_t)4096 * 512);           // [B,T,E] f32, 0.5 MB

    gemm_fused_k<<<576, 256, 0, stream>>>(topic, expo, W, battn, EPT, EPE);
    energies_k<<<1024, 256, 0, stream>>>(EPT, EPE, vsc, mask, P);
    epilogue_k<<<768, 256, 0, stream>>>(P, topic, expo, out);
}